// Round 6
// baseline (275.779 us; speedup 1.0000x reference)
//
#include <hip/hip_runtime.h>

typedef unsigned short u16;
typedef __attribute__((ext_vector_type(8))) short bf16x8;
typedef __attribute__((ext_vector_type(4))) float f32x4;

#define BATCH 4
#define SEQ   2048
#define DM    1024
#define HEADS 16
#define FEAT  16
#define HD    64
#define EXPD  273
#define EXPP  288   // padded to multiple of 32 for MFMA K
#define CHK   128
#define NC    16    // SEQ / CHK
#define BH    64    // BATCH*HEADS
#define QKS   512   // fused QK projection row stride
#define MROWS 8192  // BATCH*SEQ
#define C2    0.17677669529663687f  // 1/(sqrt(2)*sqrt(16))

__device__ __forceinline__ u16 f2b(float f) {
  union { float f; unsigned u; } v; v.f = f;
  unsigned u = v.u;
  return (u16)((u + 0x7fffu + ((u >> 16) & 1u)) >> 16);
}
__device__ __forceinline__ float b2f(u16 s) {
  union { unsigned u; float f; } v; v.u = ((unsigned)s) << 16; return v.f;
}
// HW packed bf16 convert (RTNE): lo=bf16(a), hi=bf16(b) in one VALU op.
__device__ __forceinline__ unsigned pk2b(float a, float b) {
  unsigned r;
  asm("v_cvt_pk_bf16_f32 %0, %1, %2" : "=v"(r) : "v"(a), "v"(b));
  return r;
}

typedef const unsigned int __attribute__((address_space(1)))* gas1;
typedef unsigned int __attribute__((address_space(3)))* las3;
__device__ __forceinline__ void gl_lds16(const u16* g, u16* l) {
  __builtin_amdgcn_global_load_lds((gas1)(const void*)g, (las3)(void*)l, 16, 0, 0);
}

// Fused prep: x->bf16 (0..8191), weight cast-transposes (8192..10751), bias concat (10752..10757)
__global__ __launch_bounds__(256) void prep(const float* __restrict__ x, u16* __restrict__ xb,
                                            const float* __restrict__ Wq, const float* __restrict__ Wk,
                                            const float* __restrict__ Wv, const float* __restrict__ Wo,
                                            u16* __restrict__ wqkvT, u16* __restrict__ woT,
                                            const float* __restrict__ bq, const float* __restrict__ bk,
                                            const float* __restrict__ bv, float* __restrict__ bias_all) {
  __shared__ float tile[32][33];
  int id = blockIdx.x;
  if (id < 8192) {
    int i = id * 256 + threadIdx.x;
    float4 v = ((const float4*)x)[i];
    uint2 r; r.x = pk2b(v.x, v.y); r.y = pk2b(v.z, v.w);
    ((uint2*)xb)[i] = r;
    return;
  }
  id -= 8192;
  if (id < 2560) {
    const float* src; u16* dst; int N, t;
    if (id < 256)       { src = Wq; dst = wqkvT;            N = 256;  t = id; }
    else if (id < 512)  { src = Wk; dst = wqkvT + 256 * DM; N = 256;  t = id - 256; }
    else if (id < 1536) { src = Wv; dst = wqkvT + 512 * DM; N = 1024; t = id - 512; }
    else                { src = Wo; dst = woT;              N = 1024; t = id - 1536; }
    int nt = N / 32;
    int n0 = (t % nt) * 32, k0 = (t / nt) * 32;
    int tx = threadIdx.x & 31, ty = threadIdx.x >> 5;
    for (int i = ty; i < 32; i += 8)
      tile[i][tx] = src[(size_t)(k0 + i) * N + n0 + tx];
    __syncthreads();
    for (int i = ty; i < 32; i += 8)
      dst[(size_t)(n0 + i) * DM + k0 + tx] = f2b(tile[tx][i]);
    return;
  }
  id -= 2560;
  int i = id * 256 + threadIdx.x;  // 0..1535
  float v;
  if (i < 256) v = bq[i];
  else if (i < 512) v = bk[i - 256];
  else v = bv[i - 512];
  bias_all[i] = v;
}

// Fused QKV projection: C = xb @ wqkvT^T + bias_all. N=1536.
// Tile 128x192 (grid 8x64 = 512 blocks = 2/CU balanced), per-wave 64x96 (acc 4x6).
// Double-buffered LDS, counted vmcnt(5), raw s_barrier, XOR chunk swizzle.
__global__ __launch_bounds__(256, 2) void gemmQKV(const u16* __restrict__ A, const u16* __restrict__ BT,
                                                  const float* __restrict__ bias,
                                                  float* __restrict__ qkw, u16* __restrict__ vbT) {
  __shared__ __align__(16) u16 As[2][128 * 32];
  __shared__ __align__(16) u16 Bs[2][192 * 32];
  const int tid = threadIdx.x;
  const int wave = tid >> 6, lane = tid & 63, qd = lane >> 4, ln = lane & 15;
  const int wr = (wave >> 1) * 64, wc = (wave & 1) * 96;
  const int m0 = blockIdx.y * 128, n0 = blockIdx.x * 192;
  const int K = DM;
  f32x4 acc[4][6];
#pragma unroll
  for (int i = 0; i < 4; i++)
#pragma unroll
    for (int j = 0; j < 6; j++) acc[i][j] = (f32x4){0.f, 0.f, 0.f, 0.f};
  const int sr = tid >> 2;
  const int scs = (((tid & 3) ^ ((sr >> 1) & 3))) * 8;   // u16 offset of swizzled source chunk
  const u16* gA0 = A + (size_t)(m0 + sr) * K + scs;
  const u16* gA1 = gA0 + (size_t)64 * K;
  const u16* gB0 = BT + (size_t)(n0 + sr) * K + scs;
  auto stage = [&](int buf, int kk) {
    gl_lds16(gA0 + kk, &As[buf][wave * 512]);
    gl_lds16(gA1 + kk, &As[buf][2048 + wave * 512]);
    gl_lds16(gB0 + kk,                   &Bs[buf][wave * 512]);
    gl_lds16(gB0 + (size_t)64 * K + kk,  &Bs[buf][2048 + wave * 512]);
    gl_lds16(gB0 + (size_t)128 * K + kk, &Bs[buf][4096 + wave * 512]);
  };
  const int swz = ((ln >> 1) & 3) << 3;
  auto compute = [&](int buf) {
    bf16x8 af[4], bf[6];
#pragma unroll
    for (int t = 0; t < 4; t++)
      af[t] = *(const bf16x8*)&As[buf][(wr + t * 16 + ln) * 32 + ((qd * 8) ^ swz)];
#pragma unroll
    for (int u = 0; u < 6; u++)
      bf[u] = *(const bf16x8*)&Bs[buf][(wc + u * 16 + ln) * 32 + ((qd * 8) ^ swz)];
#pragma unroll
    for (int mt = 0; mt < 4; mt++)
#pragma unroll
      for (int nt = 0; nt < 6; nt++)
        acc[mt][nt] = __builtin_amdgcn_mfma_f32_16x16x32_bf16(af[mt], bf[nt], acc[mt][nt], 0, 0, 0);
  };
  stage(0, 0);
  int buf = 0;
  for (int kk = 32; kk < K; kk += 32) {
    stage(buf ^ 1, kk);
    asm volatile("s_waitcnt vmcnt(5)" ::: "memory");
    __builtin_amdgcn_s_barrier();
    asm volatile("" ::: "memory");
    compute(buf);
    asm volatile("" ::: "memory");
    __builtin_amdgcn_s_barrier();
    buf ^= 1;
  }
  asm volatile("s_waitcnt vmcnt(0)" ::: "memory");
  __builtin_amdgcn_s_barrier();
  asm volatile("" ::: "memory");
  compute(buf);
#pragma unroll
  for (int nt = 0; nt < 6; nt++) {
    int col = n0 + wc + nt * 16 + ln;
    float bv = bias[col];
    if (col < 512) {
#pragma unroll
      for (int mt = 0; mt < 4; mt++)
#pragma unroll
        for (int r = 0; r < 4; r++) {
          int row = m0 + wr + mt * 16 + qd * 4 + r;
          qkw[(size_t)row * QKS + col] = acc[mt][nt][r] + bv;
        }
    } else {
      int vcol = col - 512;
#pragma unroll
      for (int mt = 0; mt < 4; mt++) {
        uint2 pp;
        pp.x = pk2b(acc[mt][nt][0] + bv, acc[mt][nt][1] + bv);
        pp.y = pk2b(acc[mt][nt][2] + bv, acc[mt][nt][3] + bv);
        int row0 = m0 + wr + mt * 16 + qd * 4;
        *(uint2*)&vbT[(size_t)vcol * MROWS + row0] = pp;
      }
    }
  }
}

// C = A(MxK bf16 rm) @ BT^T + bias -> fp32 rm (O projection).
__global__ __launch_bounds__(256, 3) void gemm128(const u16* __restrict__ A, const u16* __restrict__ BT,
                                                  const float* __restrict__ bias, int M, int N, int K,
                                                  float* __restrict__ outF) {
  __shared__ __align__(16) u16 As[2][128 * 32];
  __shared__ __align__(16) u16 Bs[2][128 * 32];
  const int tid = threadIdx.x;
  const int wave = tid >> 6, lane = tid & 63, qd = lane >> 4, ln = lane & 15;
  const int wr = (wave >> 1) * 64, wc = (wave & 1) * 64;
  const int m0 = blockIdx.y * 128, n0 = blockIdx.x * 128;
  f32x4 acc[4][4];
#pragma unroll
  for (int i = 0; i < 4; i++)
#pragma unroll
    for (int j = 0; j < 4; j++) acc[i][j] = (f32x4){0.f, 0.f, 0.f, 0.f};
  const int sr = tid >> 2;
  const int scs = (((tid & 3) ^ ((sr >> 1) & 3))) * 8;
  const u16* gA0 = A + (size_t)(m0 + sr) * K + scs;
  const u16* gA1 = gA0 + (size_t)64 * K;
  const u16* gB0 = BT + (size_t)(n0 + sr) * K + scs;
  const u16* gB1 = gB0 + (size_t)64 * K;
  auto stage = [&](int buf, int kk) {
    gl_lds16(gA0 + kk, &As[buf][wave * 512]);
    gl_lds16(gA1 + kk, &As[buf][2048 + wave * 512]);
    gl_lds16(gB0 + kk, &Bs[buf][wave * 512]);
    gl_lds16(gB1 + kk, &Bs[buf][2048 + wave * 512]);
  };
  const int swz = ((ln >> 1) & 3) << 3;
  auto compute = [&](int buf) {
    bf16x8 af[4], bf[4];
#pragma unroll
    for (int t = 0; t < 4; t++)
      af[t] = *(const bf16x8*)&As[buf][(wr + t * 16 + ln) * 32 + ((qd * 8) ^ swz)];
#pragma unroll
    for (int u = 0; u < 4; u++)
      bf[u] = *(const bf16x8*)&Bs[buf][(wc + u * 16 + ln) * 32 + ((qd * 8) ^ swz)];
#pragma unroll
    for (int mt = 0; mt < 4; mt++)
#pragma unroll
      for (int nt = 0; nt < 4; nt++)
        acc[mt][nt] = __builtin_amdgcn_mfma_f32_16x16x32_bf16(af[mt], bf[nt], acc[mt][nt], 0, 0, 0);
  };
  stage(0, 0);
  int buf = 0;
  for (int kk = 32; kk < K; kk += 32) {
    stage(buf ^ 1, kk);
    asm volatile("s_waitcnt vmcnt(4)" ::: "memory");
    __builtin_amdgcn_s_barrier();
    asm volatile("" ::: "memory");
    compute(buf);
    asm volatile("" ::: "memory");
    __builtin_amdgcn_s_barrier();
    buf ^= 1;
  }
  asm volatile("s_waitcnt vmcnt(0)" ::: "memory");
  __builtin_amdgcn_s_barrier();
  asm volatile("" ::: "memory");
  compute(buf);
#pragma unroll
  for (int nt = 0; nt < 4; nt++) {
    int col = n0 + wc + nt * 16 + ln;
    float bv = bias[col];
#pragma unroll
    for (int mt = 0; mt < 4; mt++)
#pragma unroll
      for (int r = 0; r < 4; r++) {
        int row = m0 + wr + mt * 16 + qd * 4 + r;
        outF[(size_t)row * N + col] = acc[mt][nt][r] + bv;
      }
  }
}

// Register-q featurize of a 32-el chunk (e = 32*KT + 16*p .. +15) into dst (contiguous 16 u16).
template<int KT>
__device__ __forceinline__ void feat_row(const float* q16, int p, u16* dst) {
  float v[16];
  if (KT == 0 && p == 0) {
    v[0] = 1.0f;
#pragma unroll
    for (int j = 1; j < 16; j++) v[j] = 0.5f * q16[j - 1];
  } else if (KT == 0) {  // p==1: e=16..31
    v[0] = 0.5f * q16[15];
    float wm = C2 * q16[0];
#pragma unroll
    for (int j = 1; j < 16; j++) v[j] = wm * q16[j - 1];
  } else {
    constexpr int c = 2 * KT;
    float wm = C2 * (p ? q16[c]     : q16[c - 1]);
    float w0 = C2 * (p ? q16[c - 1] : q16[c - 2]);
    v[0] = w0 * q16[15];
#pragma unroll
    for (int j = 1; j < 16; j++) v[j] = wm * q16[j - 1];
    if (KT == 8 && p) {  // e >= 273 -> 0
#pragma unroll
      for (int j = 1; j < 16; j++) v[j] = 0.f;
    }
  }
  unsigned w[8];
#pragma unroll
  for (int j = 0; j < 8; j++) w[j] = pk2b(v[2 * j], v[2 * j + 1]);
  *(uint4*)dst = *(uint4*)w;
  *(uint4*)(dst + 8) = *(uint4*)(w + 4);
}

// Register-k featurize for chunk_sums: mt = MTB + 2p -> buffer (mt & 3), [el][t] layout
template<int MTB>
__device__ __forceinline__ void kfeat(const float* k16, int p, int t2, u16 (*kfT)[16][136]) {
  float v[16];
  if (MTB == 0) {
    if (p == 0) {
      v[0] = 1.0f;
#pragma unroll
      for (int j = 1; j < 16; j++) v[j] = 0.5f * k16[j - 1];
    } else {
      float w0 = C2 * k16[0], wm = C2 * k16[1];
      v[0] = w0 * k16[15];
#pragma unroll
      for (int j = 1; j < 16; j++) v[j] = wm * k16[j - 1];
    }
  } else if (MTB == 1) {
    if (p == 0) {
      v[0] = 0.5f * k16[15];
      float wm = C2 * k16[0];
#pragma unroll
      for (int j = 1; j < 16; j++) v[j] = wm * k16[j - 1];
    } else {
      float w0 = C2 * k16[1], wm = C2 * k16[2];
      v[0] = w0 * k16[15];
#pragma unroll
      for (int j = 1; j < 16; j++) v[j] = wm * k16[j - 1];
    }
  } else {
    float wm = C2 * (p ? k16[MTB + 1] : k16[MTB - 1]);
    float w0 = C2 * (p ? k16[MTB]     : k16[MTB - 2]);
    v[0] = w0 * k16[15];
#pragma unroll
    for (int j = 1; j < 16; j++) v[j] = wm * k16[j - 1];
  }
  union { unsigned w[8]; u16 s[16]; } u;
#pragma unroll
  for (int j = 0; j < 8; j++) u.w[j] = pk2b(v[2 * j], v[2 * j + 1]);
  int b = 2 * p + (MTB & 1);
#pragma unroll
  for (int el = 0; el < 16; el++) kfT[b][el][t2] = u.s[el];
}

// Per (b,h,chunk of 128): ckvT[hd][e] = sum_t Kf[t][e]*V[t][hd] (bf16), ck[e] = colsum Kf (fp32)
__global__ __launch_bounds__(256) void chunk_sums(const float* __restrict__ qkw, const u16* __restrict__ vbT,
                                                  u16* __restrict__ ckvT, float* __restrict__ ck) {
  __shared__ float kl[CHK][20];
  __shared__ __align__(16) u16 kfT[4][16][136];
  const int tid = threadIdx.x;
  const int bh = blockIdx.x / NC, c = blockIdx.x % NC;
  const int b = bh >> 4, h = bh & 15;
  const int wave = tid >> 6, lane = tid & 63, qd = lane >> 4, ln = lane & 15;
  const int t2 = tid >> 1, p = tid & 1;
  const size_t rowbase = (size_t)(b * SEQ + c * CHK);
  float k16[16];
  {
    const float* kp = &qkw[(rowbase + t2) * QKS + 256 + h * FEAT];
    float4 v0 = *(const float4*)kp, v1 = *(const float4*)(kp + 4);
    float4 v2 = *(const float4*)(kp + 8), v3 = *(const float4*)(kp + 12);
    k16[0] = v0.x; k16[1] = v0.y; k16[2] = v0.z; k16[3] = v0.w;
    k16[4] = v1.x; k16[5] = v1.y; k16[6] = v1.z; k16[7] = v1.w;
    k16[8] = v2.x; k16[9] = v2.y; k16[10] = v2.z; k16[11] = v2.w;
    k16[12] = v3.x; k16[13] = v3.y; k16[14] = v3.z; k16[15] = v3.w;
    float4 h0, h1;
    if (p == 0) { h0 = v0; h1 = v1; } else { h0 = v2; h1 = v3; }
    *(float4*)&kl[t2][p * 8] = h0;
    *(float4*)&kl[t2][p * 8 + 4] = h1;
  }
  uint4 bVv[4][4];
#pragma unroll
  for (int kk2 = 0; kk2 < 4; kk2++)
#pragma unroll
    for (int nt = 0; nt < 4; nt++)
      bVv[kk2][nt] = *(const uint4*)&vbT[(size_t)(h * HD + nt * 16 + ln) * MROWS +
                                         rowbase + kk2 * 32 + qd * 8];
  const size_t obase = (size_t)(bh * NC + c) * HD;
  auto mstore = [&](int mt, int bufw) {
    f32x4 acc[4];
#pragma unroll
    for (int nt = 0; nt < 4; nt++) acc[nt] = (f32x4){0.f, 0.f, 0.f, 0.f};
#pragma unroll
    for (int kk2 = 0; kk2 < 4; kk2++) {
      bf16x8 a = *(const bf16x8*)&kfT[bufw][ln][kk2 * 32 + qd * 8];
#pragma unroll
      for (int nt = 0; nt < 4; nt++) {
        bf16x8 bb = *(const bf16x8*)&bVv[kk2][nt];
        acc[nt] = __builtin_amdgcn_mfma_f32_16x16x32_bf16(a, bb, acc[nt], 0, 0, 0);
      }
    }
#pragma unroll
    for (int nt = 0; nt < 4; nt++) {
      uint2 pp;
      pp.x = pk2b(acc[nt][0], acc[nt][1]);
      pp.y = pk2b(acc[nt][2], acc[nt][3]);
      *(uint2*)&ckvT[(obase + nt * 16 + ln) * EXPP + mt * 16 + qd * 4] = pp;
    }
  };
  __syncthreads();
  kfeat<0>(k16, p, t2, kfT); kfeat<1>(k16, p, t2, kfT);
  __syncthreads();
  mstore(wave, wave);
  __syncthreads();
  kfeat<4>(k16, p, t2, kfT); kfeat<5>(k16, p, t2, kfT);
  __syncthreads();
  mstore(4 + wave, wave);
  __syncthreads();
  kfeat<8>(k16, p, t2, kfT); kfeat<9>(k16, p, t2, kfT);
  __syncthreads();
  mstore(8 + wave, wave);
  __syncthreads();
  kfeat<12>(k16, p, t2, kfT); kfeat<13>(k16, p, t2, kfT);
  __syncthreads();
  mstore(12 + wave, wave);
  __syncthreads();
  {  // mts 16,17 -> buffers 0,1
    float v[16];
    if (p == 0) {
      float w0 = C2 * k16[14], wm = C2 * k16[15];
      v[0] = w0 * k16[15];
#pragma unroll
      for (int j = 1; j < 16; j++) v[j] = wm * k16[j - 1];
    } else {
      v[0] = C2 * k16[15] * k16[15];
#pragma unroll
      for (int j = 1; j < 16; j++) v[j] = 0.f;
    }
    union { unsigned w[8]; u16 s[16]; } u;
#pragma unroll
    for (int j = 0; j < 8; j++) u.w[j] = pk2b(v[2 * j], v[2 * j + 1]);
#pragma unroll
    for (int el = 0; el < 16; el++) kfT[p][el][t2] = u.s[el];
  }
  __syncthreads();
  if (wave < 2) mstore(16 + wave, wave);
  for (int e = tid; e < EXPP; e += 256) {
    float s = 0.f;
    if (e == 0) s = (float)CHK;
    else if (e < 17) { float t = 0.f; for (int tt = 0; tt < CHK; tt++) t += kl[tt][e - 1]; s = 0.5f * t; }
    else if (e < EXPD) {
      int u = e - 17, i0 = u >> 4, j0 = u & 15; float t = 0.f;
      for (int tt = 0; tt < CHK; tt++) t += kl[tt][i0] * kl[tt][j0];
      s = C2 * t;
    }
    ck[(size_t)(bh * NC + c) * EXPP + e] = s;
  }
}

// Exclusive prefix over chunks (in place, bf16) on ckvT; inclusive final -> out_kv.
__global__ __launch_bounds__(256) void kv_prefix(u16* __restrict__ ckvT, const float* __restrict__ kv0,
                                                 float* __restrict__ out_kv,
                                                 float* __restrict__ ck, const float* __restrict__ k0,
                                                 float* __restrict__ out_k) {
  const int tid = threadIdx.x;
  const int bh = blockIdx.x / 10, eg = blockIdx.x % 10;
  if (eg == 9) {
    for (int e = tid; e < EXPP; e += 256) {
      float S = (e < EXPD) ? k0[(size_t)bh * EXPD + e] : 0.f;
      for (int c = 0; c < NC; c++) {
        size_t idx = ((size_t)bh * NC + c) * EXPP + e;
        float v = ck[idx];
        ck[idx] = S;
        S += v;
      }
      if (e < EXPD) out_k[(size_t)bh * EXPD + e] = S;
    }
    return;
  }
  const int hd = tid >> 2;
  const int e0 = eg * 32 + (tid & 3) * 8;
  float S[8];
#pragma unroll
  for (int j = 0; j < 8; j++) {
    int e = e0 + j;
    S[j] = (e < EXPD) ? kv0[((size_t)bh * EXPD + e) * HD + hd] : 0.f;
  }
  u16* base = ckvT + ((size_t)bh * NC * HD + hd) * EXPP + e0;
  const size_t cstride = (size_t)HD * EXPP;
  uint4 v0 = *(const uint4*)base;
  uint4 v1 = *(const uint4*)(base + cstride);
  for (int c = 0; c < NC; c++) {
    uint4 vn = v1;
    if (c + 2 < NC) vn = *(const uint4*)(base + (size_t)(c + 2) * cstride);
    union { uint4 q; unsigned w[4]; } pk;
#pragma unroll
    for (int j = 0; j < 4; j++) pk.w[j] = pk2b(S[2 * j], S[2 * j + 1]);
    *(uint4*)(base + (size_t)c * cstride) = pk.q;
    union { uint4 q; u16 s[8]; } vv; vv.q = v0;
#pragma unroll
    for (int j = 0; j < 8; j++) S[j] += b2f(vv.s[j]);
    v0 = v1; v1 = vn;
  }
#pragma unroll
  for (int j = 0; j < 8; j++) {
    int e = e0 + j;
    if (e < EXPD) out_kv[((size_t)bh * EXPD + e) * HD + hd] = S[j];
  }
}

// Per (b,h,chunk of 128): O = (Qf@S + mask_incl(poly(QK^T))@V) / den.
// R5: R2's K-step body (batched bQ[8] ds_reads -> feat -> MFMAs) + rolling
// bSv[3]; st2=0 scores split into 2x accU[4] (alA doesn't overlay qlb/klb so
// split is safe); bVv loads sunk to after st2=1 MFMAs. Goal: true VGPR <= 128.
__global__ __launch_bounds__(256) void out_chunk(const float* __restrict__ qkw, const u16* __restrict__ vbT,
                                                 const u16* __restrict__ ckvT, const float* __restrict__ ck,
                                                 u16* __restrict__ ob) {
  __shared__ __align__(16) u16 pool[19456];   // 38,912 B
  __shared__ float kstl[EXPP];
  __shared__ float denl[CHK];
  u16 (*qlb)[40]  = (u16(*)[40])pool;                 // 128x40, cols 16..31 zero
  u16 (*klb)[32]  = (u16(*)[32])(pool + 5120);        // 128x32, cols 16..31 zero (NaN*0 guard)
  u16 (*qfs0)[40] = (u16(*)[40])(pool + 9216);        // Qf double buffer 0
  u16 (*qfs1)[40] = (u16(*)[40])(pool + 14336);       // Qf double buffer 1
  u16 (*alB)[72]  = (u16(*)[72])pool;                 // scores s=64..127 (overlays qlb/klb)
  u16 (*alA)[72]  = (u16(*)[72])(pool + 9216);        // scores s=0..63   (overlays qfs0/qfs1)
  const int tid = threadIdx.x;
  const int bh = blockIdx.x / NC, c = blockIdx.x % NC;
  const int b = bh >> 4, h = bh & 15;
  const int wave = tid >> 6, lane = tid & 63, qd = lane >> 4, ln = lane & 15;
  const int t2 = tid >> 1, p = tid & 1;
  const size_t rowbase = (size_t)(b * SEQ + c * CHK);
  float q16[16];
  {
    const float* qp = &qkw[(rowbase + t2) * QKS + h * FEAT];
    float4 v0 = *(const float4*)qp, v1 = *(const float4*)(qp + 4);
    float4 v2 = *(const float4*)(qp + 8), v3 = *(const float4*)(qp + 12);
    q16[0] = v0.x; q16[1] = v0.y; q16[2] = v0.z; q16[3] = v0.w;
    q16[4] = v1.x; q16[5] = v1.y; q16[6] = v1.z; q16[7] = v1.w;
    q16[8] = v2.x; q16[9] = v2.y; q16[10] = v2.z; q16[11] = v2.w;
    q16[12] = v3.x; q16[13] = v3.y; q16[14] = v3.z; q16[15] = v3.w;
    unsigned qw[4];
#pragma unroll
    for (int j = 0; j < 4; j++) qw[j] = pk2b(q16[p * 8 + 2 * j], q16[p * 8 + 2 * j + 1]);
    *(uint4*)&qlb[t2][p * 8] = *(uint4*)qw;
    *(uint4*)&qlb[t2][16 + p * 8] = (uint4){0u, 0u, 0u, 0u};
    const float* kp = &qkw[(rowbase + t2) * QKS + 256 + h * FEAT + p * 8];
    float4 k0v = *(const float4*)kp, k1v = *(const float4*)(kp + 4);
    unsigned kw[4] = {pk2b(k0v.x, k0v.y), pk2b(k0v.z, k0v.w),
                      pk2b(k1v.x, k1v.y), pk2b(k1v.z, k1v.w)};
    *(uint4*)&klb[t2][p * 8] = *(uint4*)kw;
    *(uint4*)&klb[t2][16 + p * 8] = (uint4){0u, 0u, 0u, 0u};
  }
  const size_t cbase = (size_t)(bh * NC + c);
  for (int e = tid; e < EXPP; e += 256) kstl[e] = ck[cbase * EXPP + e];
  const u16* sptr = ckvT + (cbase * HD + wave * 16 + ln) * EXPP + qd * 8;
  // rolling 3-slot S-fragment buffer, prefetch distance 2 (all indices static)
  uint4 bSv[3];
  bSv[0] = *(const uint4*)(sptr + 0 * 32);
  bSv[1] = *(const uint4*)(sptr + 1 * 32);
  feat_row<0>(q16, p, &qfs0[t2][p * 16]);
  f32x4 accO[8];
#pragma unroll
  for (int nt = 0; nt < 8; nt++) accO[nt] = (f32x4){0.f, 0.f, 0.f, 0.f};
  // one barrier per K-step: {barrier; prefetch S[KT+2]; batch bQ[8]; feat NXT; MFMAs}
#define KSTEP(KT, CUR, NXT)                                                                \
  {                                                                                        \
    __syncthreads();                                                                       \
    if ((KT) + 2 <= 8) bSv[((KT) + 2) % 3] = *(const uint4*)(sptr + ((KT) + 2) * 32);      \
    bf16x8 bQ[8];                                                                          \
    _Pragma("unroll")                                                                      \
    for (int nt = 0; nt < 8; nt++) bQ[nt] = *(const bf16x8*)&CUR[nt * 16 + ln][qd * 8];    \
    feat_row<(KT) + 1>(q16, p, &NXT[t2][p * 16]);                                          \
    bf16x8 aS = *(const bf16x8*)&bSv[(KT) % 3];                                            \
    _Pragma("unroll")                                                                      \
    for (int nt = 0; nt < 8; nt++)                                                         \
      accO[nt] = __builtin_amdgcn_mfma_f32_16x16x32_bf16(aS, bQ[nt], accO[nt], 0, 0, 0);   \
  }
  KSTEP(0, qfs0, qfs1) KSTEP(1, qfs1, qfs0) KSTEP(2, qfs0, qfs1) KSTEP(3, qfs1, qfs0)
  KSTEP(4, qfs0, qfs1) KSTEP(5, qfs1, qfs0) KSTEP(6, qfs0, qfs1) KSTEP(7, qfs1, qfs0)
#undef KSTEP
  {  // final K-step (KT=8, buffer qfs0, no next featurize)
    __syncthreads();
    bf16x8 aS = *(const bf16x8*)&bSv[8 % 3];
#pragma unroll
    for (int nt = 0; nt < 8; nt++) {
      bf16x8 bQ = *(const bf16x8*)&qfs0[nt * 16 + ln][qd * 8];
      accO[nt] = __builtin_amdgcn_mfma_f32_16x16x32_bf16(aS, bQ, accO[nt], 0, 0, 0);
    }
  }
  __syncthreads();   // all waves done reading qfs -> alA region free
  // hoisted denominator polynomial (q16 dies here; before scores)
  float s_poly;
  {
    float s = 0.f;
#pragma unroll
    for (int i2 = 0; i2 < 8; i2++) {
      int i = p * 8 + i2;
      float inner = 0.f;
#pragma unroll
      for (int j = 0; j < 16; j++) inner += q16[j] * kstl[17 + i * 16 + j];
      s += q16[i] * inner;
    }
    s *= C2;
    float s1 = 0.f;
#pragma unroll
    for (int j2 = 0; j2 < 8; j2++) s1 += q16[p * 8 + j2] * kstl[1 + p * 8 + j2];
    s += 0.5f * s1;
    if (p == 0) s += kstl[0] + 1e-6f;
    s_poly = s;
  }
  // scores st2=0: s-tile = wave (s 0..63) -> alA. Split into 2x accU[4]
  // (alA overlays qfs only, not qlb/klb, so interleaved writes are safe).
  {
    bf16x8 aK = *(const bf16x8*)&klb[wave * 16 + ln][qd * 8];
#pragma unroll
    for (int nn = 0; nn < 2; nn++) {
      f32x4 accU[4];
#pragma unroll
      for (int j = 0; j < 4; j++) {
        bf16x8 bQ = *(const bf16x8*)&qlb[(nn * 4 + j) * 16 + ln][qd * 8];
        accU[j] = __builtin_amdgcn_mfma_f32_16x16x32_bf16(aK, bQ, (f32x4){0.f, 0.f, 0.f, 0.f}, 0, 0, 0);
      }
#pragma unroll
      for (int j = 0; j < 4; j++) {
        int t = (nn * 4 + j) * 16 + ln, sb = wave * 16 + qd * 4;
        float scm[4];
#pragma unroll
        for (int r = 0; r < 4; r++) {
          float u = accU[j][r];
          float sc = 1.f + 0.25f * u + 0.03125f * u * u;
          scm[r] = (sb + r <= t) ? sc : 0.f;
        }
        uint2 pp; pp.x = pk2b(scm[0], scm[1]); pp.y = pk2b(scm[2], scm[3]);
        *(uint2*)&alA[t][sb] = pp;
      }
    }
  }
  // scores st2=1: s-tile = wave+4 (s 64..127) -> alB (overlays qlb/klb; must
  // finish ALL reads before any write -> accU[8] held across the barrier).
  {
    f32x4 accU[8];
    bf16x8 aK = *(const bf16x8*)&klb[(wave + 4) * 16 + ln][qd * 8];
#pragma unroll
    for (int nt = 0; nt < 8; nt++) {
      bf16x8 bQ = *(const bf16x8*)&qlb[nt * 16 + ln][qd * 8];
      accU[nt] = __builtin_amdgcn_mfma_f32_16x16x32_bf16(aK, bQ, (f32x4){0.f, 0.f, 0.f, 0.f}, 0, 0, 0);
    }
    // V fragments issued here: latency hides under alB pack/write + barrier
    uint4 bVv[4];
#pragma unroll
    for (int kk2 = 0; kk2 < 4; kk2++)
      bVv[kk2] = *(const uint4*)&vbT[(size_t)(h * HD + wave * 16 + ln) * MROWS +
                                     rowbase + kk2 * 32 + qd * 8];
    __syncthreads();   // all qlb/klb reads complete before alB overwrite
#pragma unroll
    for (int nt = 0; nt < 8; nt++) {
      int t = nt * 16 + ln, sbl = wave * 16 + qd * 4;
      float scm[4];
#pragma unroll
      for (int r = 0; r < 4; r++) {
        float u = accU[nt][r];
        float sc = 1.f + 0.25f * u + 0.03125f * u * u;
        scm[r] = (64 + sbl + r <= t) ? sc : 0.f;
      }
      uint2 pp; pp.x = pk2b(scm[0], scm[1]); pp.y = pk2b(scm[2], scm[3]);
      *(uint2*)&alB[t][sbl] = pp;
    }
    __syncthreads();
    // A@V: A = V frags (registers), B = al rows
#pragma unroll
    for (int kk2 = 0; kk2 < 4; kk2++) {
      bf16x8 aV = *(const bf16x8*)&bVv[kk2];
#pragma unroll
      for (int nt = 0; nt < 8; nt++) {
        bf16x8 bA = (kk2 < 2) ? *(const bf16x8*)&alA[nt * 16 + ln][kk2 * 32 + qd * 8]
                              : *(const bf16x8*)&alB[nt * 16 + ln][(kk2 - 2) * 32 + qd * 8];
        accO[nt] = __builtin_amdgcn_mfma_f32_16x16x32_bf16(aV, bA, accO[nt], 0, 0, 0);
      }
    }
  }
  // denominator: row-sum of al + hoisted polynomial
  {
    const u16* arow = p ? &alB[t2][0] : &alA[t2][0];
    float da = 0.f;
#pragma unroll
    for (int sb = 0; sb < 8; sb++) {
      union { uint4 q; u16 hh[8]; } uu;
      uu.q = *(const uint4*)(arow + sb * 8);
#pragma unroll
      for (int j = 0; j < 8; j++) da += b2f(uu.hh[j]);
    }
    float s = s_poly + da;
    s += __shfl_xor(s, 1);
    if (p == 0) denl[t2] = s;
  }
  __syncthreads();
  // output: lane holds hd = wave*16+qd*4+r, t = nt*16+ln -> packed uint2 along hd
#pragma unroll
  for (int nt = 0; nt < 8; nt++) {
    int t = nt * 16 + ln;
    float rd = 1.0f / denl[t];
    uint2 pp;
    pp.x = pk2b(accO[nt][0] * rd, accO[nt][1] * rd);
    pp.y = pk2b(accO[nt][2] * rd, accO[nt][3] * rd);
    *(uint2*)&ob[(rowbase + t) * DM + h * HD + wave * 16 + qd * 4] = pp;
  }
}

extern "C" void kernel_launch(void* const* d_in, const int* in_sizes, int n_in,
                              void* d_out, int out_size, void* d_ws, size_t ws_size,
                              hipStream_t stream) {
  (void)in_sizes; (void)n_in; (void)out_size;
  const float* x   = (const float*)d_in[0];
  const float* kv0 = (const float*)d_in[1];
  const float* k0  = (const float*)d_in[2];
  const float* bq  = (const float*)d_in[4];
  const float* bk  = (const float*)d_in[6];
  const float* bv  = (const float*)d_in[8];
  const float* bo  = (const float*)d_in[10];
  float* out = (float*)d_out;
  char* ws = (char*)d_ws;
  size_t off = 0;
  auto take = [&](size_t bytes) { char* p = ws + off; off += (bytes + 255) & ~(size_t)255; return p; };
  u16*   xb     = (u16*)  take((size_t)BATCH * SEQ * DM * 2);
  u16*   wqkvT  = (u16*)  take((size_t)1536 * DM * 2);
  u16*   woT    = (u16*)  take((size_t)DM * DM * 2);
  float* bias_a = (float*)take((size_t)1536 * 4);
  float* qkw    = (float*)take((size_t)BATCH * SEQ * QKS * 4);
  u16*   vbT    = (u16*)  take((size_t)BATCH * SEQ * DM * 2);
  u16*   ckvT   = (u16*)  take((size_t)BH * NC * EXPP * HD * 2);
  float* ck     = (float*)take((size_t)BH * NC * EXPP * 4);
  u16*   ob     = (u16*)  take((size_t)BATCH * SEQ * DM * 2);
  if (off > ws_size) return;

  float* out_kv = out + (size_t)BATCH * SEQ * DM;
  float* out_k  = out_kv + (size_t)BH * EXPD * HD;

  prep<<<8192 + 2560 + 6, 256, 0, stream>>>(x, xb,
      (const float*)d_in[3], (const float*)d_in[5], (const float*)d_in[7], (const float*)d_in[9],
      wqkvT, woT, bq, bk, bv, bias_a);

  gemmQKV<<<dim3(8, 64), 256, 0, stream>>>(xb, wqkvT, bias_a, qkw, vbT);

  chunk_sums<<<BH * NC, 256, 0, stream>>>(qkw, vbT, ckvT, ck);
  kv_prefix<<<BH * 10, 256, 0, stream>>>(ckvT, kv0, out_kv, ck, k0, out_k);
  out_chunk<<<BH * NC, 256, 0, stream>>>(qkw, vbT, ckvT, ck, ob);

  gemm128<<<dim3(8, 64), 256, 0, stream>>>(ob, woT, bo, MROWS, DM, DM, out);
}

// Round 7
// 274.640 us; speedup vs baseline: 1.0041x; 1.0041x over previous
//
#include <hip/hip_runtime.h>

typedef unsigned short u16;
typedef __attribute__((ext_vector_type(8))) short bf16x8;
typedef __attribute__((ext_vector_type(4))) float f32x4;

#define BATCH 4
#define SEQ   2048
#define DM    1024
#define HEADS 16
#define FEAT  16
#define HD    64
#define EXPD  273
#define EXPP  288   // padded to multiple of 32 for MFMA K
#define CHK   128
#define NC    16    // SEQ / CHK
#define BH    64    // BATCH*HEADS
#define QKS   512   // fused QK projection row stride
#define MROWS 8192  // BATCH*SEQ
#define C2    0.17677669529663687f  // 1/(sqrt(2)*sqrt(16))

__device__ __forceinline__ u16 f2b(float f) {
  union { float f; unsigned u; } v; v.f = f;
  unsigned u = v.u;
  return (u16)((u + 0x7fffu + ((u >> 16) & 1u)) >> 16);
}
__device__ __forceinline__ float b2f(u16 s) {
  union { unsigned u; float f; } v; v.u = ((unsigned)s) << 16; return v.f;
}
// HW packed bf16 convert (RTNE): lo=bf16(a), hi=bf16(b) in one VALU op.
__device__ __forceinline__ unsigned pk2b(float a, float b) {
  unsigned r;
  asm("v_cvt_pk_bf16_f32 %0, %1, %2" : "=v"(r) : "v"(a), "v"(b));
  return r;
}

typedef const unsigned int __attribute__((address_space(1)))* gas1;
typedef unsigned int __attribute__((address_space(3)))* las3;
__device__ __forceinline__ void gl_lds16(const u16* g, u16* l) {
  __builtin_amdgcn_global_load_lds((gas1)(const void*)g, (las3)(void*)l, 16, 0, 0);
}

// Fused prep: x->bf16 (0..8191), weight cast-transposes (8192..10751), bias concat (10752..10757)
__global__ __launch_bounds__(256) void prep(const float* __restrict__ x, u16* __restrict__ xb,
                                            const float* __restrict__ Wq, const float* __restrict__ Wk,
                                            const float* __restrict__ Wv, const float* __restrict__ Wo,
                                            u16* __restrict__ wqkvT, u16* __restrict__ woT,
                                            const float* __restrict__ bq, const float* __restrict__ bk,
                                            const float* __restrict__ bv, float* __restrict__ bias_all) {
  __shared__ float tile[32][33];
  int id = blockIdx.x;
  if (id < 8192) {
    int i = id * 256 + threadIdx.x;
    float4 v = ((const float4*)x)[i];
    uint2 r; r.x = pk2b(v.x, v.y); r.y = pk2b(v.z, v.w);
    ((uint2*)xb)[i] = r;
    return;
  }
  id -= 8192;
  if (id < 2560) {
    const float* src; u16* dst; int N, t;
    if (id < 256)       { src = Wq; dst = wqkvT;            N = 256;  t = id; }
    else if (id < 512)  { src = Wk; dst = wqkvT + 256 * DM; N = 256;  t = id - 256; }
    else if (id < 1536) { src = Wv; dst = wqkvT + 512 * DM; N = 1024; t = id - 512; }
    else                { src = Wo; dst = woT;              N = 1024; t = id - 1536; }
    int nt = N / 32;
    int n0 = (t % nt) * 32, k0 = (t / nt) * 32;
    int tx = threadIdx.x & 31, ty = threadIdx.x >> 5;
    for (int i = ty; i < 32; i += 8)
      tile[i][tx] = src[(size_t)(k0 + i) * N + n0 + tx];
    __syncthreads();
    for (int i = ty; i < 32; i += 8)
      dst[(size_t)(n0 + i) * DM + k0 + tx] = f2b(tile[tx][i]);
    return;
  }
  id -= 2560;
  int i = id * 256 + threadIdx.x;  // 0..1535
  float v;
  if (i < 256) v = bq[i];
  else if (i < 512) v = bk[i - 256];
  else v = bv[i - 512];
  bias_all[i] = v;
}

// Fused QKV projection: C = xb @ wqkvT^T + bias_all. N=1536.
// Tile 128x192 (grid 8x64 = 512 blocks = 2/CU balanced), per-wave 64x96 (acc 4x6).
// Double-buffered LDS, counted vmcnt(5), raw s_barrier, XOR chunk swizzle.
__global__ __launch_bounds__(256, 2) void gemmQKV(const u16* __restrict__ A, const u16* __restrict__ BT,
                                                  const float* __restrict__ bias,
                                                  float* __restrict__ qkw, u16* __restrict__ vbT) {
  __shared__ __align__(16) u16 As[2][128 * 32];
  __shared__ __align__(16) u16 Bs[2][192 * 32];
  const int tid = threadIdx.x;
  const int wave = tid >> 6, lane = tid & 63, qd = lane >> 4, ln = lane & 15;
  const int wr = (wave >> 1) * 64, wc = (wave & 1) * 96;
  const int m0 = blockIdx.y * 128, n0 = blockIdx.x * 192;
  const int K = DM;
  f32x4 acc[4][6];
#pragma unroll
  for (int i = 0; i < 4; i++)
#pragma unroll
    for (int j = 0; j < 6; j++) acc[i][j] = (f32x4){0.f, 0.f, 0.f, 0.f};
  const int sr = tid >> 2;
  const int scs = (((tid & 3) ^ ((sr >> 1) & 3))) * 8;   // u16 offset of swizzled source chunk
  const u16* gA0 = A + (size_t)(m0 + sr) * K + scs;
  const u16* gA1 = gA0 + (size_t)64 * K;
  const u16* gB0 = BT + (size_t)(n0 + sr) * K + scs;
  auto stage = [&](int buf, int kk) {
    gl_lds16(gA0 + kk, &As[buf][wave * 512]);
    gl_lds16(gA1 + kk, &As[buf][2048 + wave * 512]);
    gl_lds16(gB0 + kk,                   &Bs[buf][wave * 512]);
    gl_lds16(gB0 + (size_t)64 * K + kk,  &Bs[buf][2048 + wave * 512]);
    gl_lds16(gB0 + (size_t)128 * K + kk, &Bs[buf][4096 + wave * 512]);
  };
  const int swz = ((ln >> 1) & 3) << 3;
  auto compute = [&](int buf) {
    bf16x8 af[4], bf[6];
#pragma unroll
    for (int t = 0; t < 4; t++)
      af[t] = *(const bf16x8*)&As[buf][(wr + t * 16 + ln) * 32 + ((qd * 8) ^ swz)];
#pragma unroll
    for (int u = 0; u < 6; u++)
      bf[u] = *(const bf16x8*)&Bs[buf][(wc + u * 16 + ln) * 32 + ((qd * 8) ^ swz)];
#pragma unroll
    for (int mt = 0; mt < 4; mt++)
#pragma unroll
      for (int nt = 0; nt < 6; nt++)
        acc[mt][nt] = __builtin_amdgcn_mfma_f32_16x16x32_bf16(af[mt], bf[nt], acc[mt][nt], 0, 0, 0);
  };
  stage(0, 0);
  int buf = 0;
  for (int kk = 32; kk < K; kk += 32) {
    stage(buf ^ 1, kk);
    asm volatile("s_waitcnt vmcnt(5)" ::: "memory");
    __builtin_amdgcn_s_barrier();
    asm volatile("" ::: "memory");
    compute(buf);
    asm volatile("" ::: "memory");
    __builtin_amdgcn_s_barrier();
    buf ^= 1;
  }
  asm volatile("s_waitcnt vmcnt(0)" ::: "memory");
  __builtin_amdgcn_s_barrier();
  asm volatile("" ::: "memory");
  compute(buf);
#pragma unroll
  for (int nt = 0; nt < 6; nt++) {
    int col = n0 + wc + nt * 16 + ln;
    float bv = bias[col];
    if (col < 512) {
#pragma unroll
      for (int mt = 0; mt < 4; mt++)
#pragma unroll
        for (int r = 0; r < 4; r++) {
          int row = m0 + wr + mt * 16 + qd * 4 + r;
          qkw[(size_t)row * QKS + col] = acc[mt][nt][r] + bv;
        }
    } else {
      int vcol = col - 512;
#pragma unroll
      for (int mt = 0; mt < 4; mt++) {
        uint2 pp;
        pp.x = pk2b(acc[mt][nt][0] + bv, acc[mt][nt][1] + bv);
        pp.y = pk2b(acc[mt][nt][2] + bv, acc[mt][nt][3] + bv);
        int row0 = m0 + wr + mt * 16 + qd * 4;
        *(uint2*)&vbT[(size_t)vcol * MROWS + row0] = pp;
      }
    }
  }
}

// C = A(MxK bf16 rm) @ BT^T + bias -> fp32 rm (O projection).
__global__ __launch_bounds__(256, 3) void gemm128(const u16* __restrict__ A, const u16* __restrict__ BT,
                                                  const float* __restrict__ bias, int M, int N, int K,
                                                  float* __restrict__ outF) {
  __shared__ __align__(16) u16 As[2][128 * 32];
  __shared__ __align__(16) u16 Bs[2][128 * 32];
  const int tid = threadIdx.x;
  const int wave = tid >> 6, lane = tid & 63, qd = lane >> 4, ln = lane & 15;
  const int wr = (wave >> 1) * 64, wc = (wave & 1) * 64;
  const int m0 = blockIdx.y * 128, n0 = blockIdx.x * 128;
  f32x4 acc[4][4];
#pragma unroll
  for (int i = 0; i < 4; i++)
#pragma unroll
    for (int j = 0; j < 4; j++) acc[i][j] = (f32x4){0.f, 0.f, 0.f, 0.f};
  const int sr = tid >> 2;
  const int scs = (((tid & 3) ^ ((sr >> 1) & 3))) * 8;
  const u16* gA0 = A + (size_t)(m0 + sr) * K + scs;
  const u16* gA1 = gA0 + (size_t)64 * K;
  const u16* gB0 = BT + (size_t)(n0 + sr) * K + scs;
  const u16* gB1 = gB0 + (size_t)64 * K;
  auto stage = [&](int buf, int kk) {
    gl_lds16(gA0 + kk, &As[buf][wave * 512]);
    gl_lds16(gA1 + kk, &As[buf][2048 + wave * 512]);
    gl_lds16(gB0 + kk, &Bs[buf][wave * 512]);
    gl_lds16(gB1 + kk, &Bs[buf][2048 + wave * 512]);
  };
  const int swz = ((ln >> 1) & 3) << 3;
  auto compute = [&](int buf) {
    bf16x8 af[4], bf[4];
#pragma unroll
    for (int t = 0; t < 4; t++)
      af[t] = *(const bf16x8*)&As[buf][(wr + t * 16 + ln) * 32 + ((qd * 8) ^ swz)];
#pragma unroll
    for (int u = 0; u < 4; u++)
      bf[u] = *(const bf16x8*)&Bs[buf][(wc + u * 16 + ln) * 32 + ((qd * 8) ^ swz)];
#pragma unroll
    for (int mt = 0; mt < 4; mt++)
#pragma unroll
      for (int nt = 0; nt < 4; nt++)
        acc[mt][nt] = __builtin_amdgcn_mfma_f32_16x16x32_bf16(af[mt], bf[nt], acc[mt][nt], 0, 0, 0);
  };
  stage(0, 0);
  int buf = 0;
  for (int kk = 32; kk < K; kk += 32) {
    stage(buf ^ 1, kk);
    asm volatile("s_waitcnt vmcnt(4)" ::: "memory");
    __builtin_amdgcn_s_barrier();
    asm volatile("" ::: "memory");
    compute(buf);
    asm volatile("" ::: "memory");
    __builtin_amdgcn_s_barrier();
    buf ^= 1;
  }
  asm volatile("s_waitcnt vmcnt(0)" ::: "memory");
  __builtin_amdgcn_s_barrier();
  asm volatile("" ::: "memory");
  compute(buf);
#pragma unroll
  for (int nt = 0; nt < 4; nt++) {
    int col = n0 + wc + nt * 16 + ln;
    float bv = bias[col];
#pragma unroll
    for (int mt = 0; mt < 4; mt++)
#pragma unroll
      for (int r = 0; r < 4; r++) {
        int row = m0 + wr + mt * 16 + qd * 4 + r;
        outF[(size_t)row * N + col] = acc[mt][nt][r] + bv;
      }
  }
}

// Register-q featurize of a 32-el chunk (e = 32*KT + 16*p .. +15) into dst (contiguous 16 u16).
template<int KT>
__device__ __forceinline__ void feat_row(const float* q16, int p, u16* dst) {
  float v[16];
  if (KT == 0 && p == 0) {
    v[0] = 1.0f;
#pragma unroll
    for (int j = 1; j < 16; j++) v[j] = 0.5f * q16[j - 1];
  } else if (KT == 0) {  // p==1: e=16..31
    v[0] = 0.5f * q16[15];
    float wm = C2 * q16[0];
#pragma unroll
    for (int j = 1; j < 16; j++) v[j] = wm * q16[j - 1];
  } else {
    constexpr int c = 2 * KT;
    float wm = C2 * (p ? q16[c]     : q16[c - 1]);
    float w0 = C2 * (p ? q16[c - 1] : q16[c - 2]);
    v[0] = w0 * q16[15];
#pragma unroll
    for (int j = 1; j < 16; j++) v[j] = wm * q16[j - 1];
    if (KT == 8 && p) {  // e >= 273 -> 0
#pragma unroll
      for (int j = 1; j < 16; j++) v[j] = 0.f;
    }
  }
  unsigned w[8];
#pragma unroll
  for (int j = 0; j < 8; j++) w[j] = pk2b(v[2 * j], v[2 * j + 1]);
  *(uint4*)dst = *(uint4*)w;
  *(uint4*)(dst + 8) = *(uint4*)(w + 4);
}

// Register-k featurize for chunk_sums: mt = MTB + 2p -> buffer (mt & 3), [el][t] layout
template<int MTB>
__device__ __forceinline__ void kfeat(const float* k16, int p, int t2, u16 (*kfT)[16][136]) {
  float v[16];
  if (MTB == 0) {
    if (p == 0) {
      v[0] = 1.0f;
#pragma unroll
      for (int j = 1; j < 16; j++) v[j] = 0.5f * k16[j - 1];
    } else {
      float w0 = C2 * k16[0], wm = C2 * k16[1];
      v[0] = w0 * k16[15];
#pragma unroll
      for (int j = 1; j < 16; j++) v[j] = wm * k16[j - 1];
    }
  } else if (MTB == 1) {
    if (p == 0) {
      v[0] = 0.5f * k16[15];
      float wm = C2 * k16[0];
#pragma unroll
      for (int j = 1; j < 16; j++) v[j] = wm * k16[j - 1];
    } else {
      float w0 = C2 * k16[1], wm = C2 * k16[2];
      v[0] = w0 * k16[15];
#pragma unroll
      for (int j = 1; j < 16; j++) v[j] = wm * k16[j - 1];
    }
  } else {
    float wm = C2 * (p ? k16[MTB + 1] : k16[MTB - 1]);
    float w0 = C2 * (p ? k16[MTB]     : k16[MTB - 2]);
    v[0] = w0 * k16[15];
#pragma unroll
    for (int j = 1; j < 16; j++) v[j] = wm * k16[j - 1];
  }
  union { unsigned w[8]; u16 s[16]; } u;
#pragma unroll
  for (int j = 0; j < 8; j++) u.w[j] = pk2b(v[2 * j], v[2 * j + 1]);
  int b = 2 * p + (MTB & 1);
#pragma unroll
  for (int el = 0; el < 16; el++) kfT[b][el][t2] = u.s[el];
}

// Per (b,h,chunk of 128): ckvT[hd][e] = sum_t Kf[t][e]*V[t][hd] (bf16), ck[e] = colsum Kf (fp32)
__global__ __launch_bounds__(256) void chunk_sums(const float* __restrict__ qkw, const u16* __restrict__ vbT,
                                                  u16* __restrict__ ckvT, float* __restrict__ ck) {
  __shared__ float kl[CHK][20];
  __shared__ __align__(16) u16 kfT[4][16][136];
  const int tid = threadIdx.x;
  const int bh = blockIdx.x / NC, c = blockIdx.x % NC;
  const int b = bh >> 4, h = bh & 15;
  const int wave = tid >> 6, lane = tid & 63, qd = lane >> 4, ln = lane & 15;
  const int t2 = tid >> 1, p = tid & 1;
  const size_t rowbase = (size_t)(b * SEQ + c * CHK);
  float k16[16];
  {
    const float* kp = &qkw[(rowbase + t2) * QKS + 256 + h * FEAT];
    float4 v0 = *(const float4*)kp, v1 = *(const float4*)(kp + 4);
    float4 v2 = *(const float4*)(kp + 8), v3 = *(const float4*)(kp + 12);
    k16[0] = v0.x; k16[1] = v0.y; k16[2] = v0.z; k16[3] = v0.w;
    k16[4] = v1.x; k16[5] = v1.y; k16[6] = v1.z; k16[7] = v1.w;
    k16[8] = v2.x; k16[9] = v2.y; k16[10] = v2.z; k16[11] = v2.w;
    k16[12] = v3.x; k16[13] = v3.y; k16[14] = v3.z; k16[15] = v3.w;
    float4 h0, h1;
    if (p == 0) { h0 = v0; h1 = v1; } else { h0 = v2; h1 = v3; }
    *(float4*)&kl[t2][p * 8] = h0;
    *(float4*)&kl[t2][p * 8 + 4] = h1;
  }
  uint4 bVv[4][4];
#pragma unroll
  for (int kk2 = 0; kk2 < 4; kk2++)
#pragma unroll
    for (int nt = 0; nt < 4; nt++)
      bVv[kk2][nt] = *(const uint4*)&vbT[(size_t)(h * HD + nt * 16 + ln) * MROWS +
                                         rowbase + kk2 * 32 + qd * 8];
  const size_t obase = (size_t)(bh * NC + c) * HD;
  auto mstore = [&](int mt, int bufw) {
    f32x4 acc[4];
#pragma unroll
    for (int nt = 0; nt < 4; nt++) acc[nt] = (f32x4){0.f, 0.f, 0.f, 0.f};
#pragma unroll
    for (int kk2 = 0; kk2 < 4; kk2++) {
      bf16x8 a = *(const bf16x8*)&kfT[bufw][ln][kk2 * 32 + qd * 8];
#pragma unroll
      for (int nt = 0; nt < 4; nt++) {
        bf16x8 bb = *(const bf16x8*)&bVv[kk2][nt];
        acc[nt] = __builtin_amdgcn_mfma_f32_16x16x32_bf16(a, bb, acc[nt], 0, 0, 0);
      }
    }
#pragma unroll
    for (int nt = 0; nt < 4; nt++) {
      uint2 pp;
      pp.x = pk2b(acc[nt][0], acc[nt][1]);
      pp.y = pk2b(acc[nt][2], acc[nt][3]);
      *(uint2*)&ckvT[(obase + nt * 16 + ln) * EXPP + mt * 16 + qd * 4] = pp;
    }
  };
  __syncthreads();
  kfeat<0>(k16, p, t2, kfT); kfeat<1>(k16, p, t2, kfT);
  __syncthreads();
  mstore(wave, wave);
  __syncthreads();
  kfeat<4>(k16, p, t2, kfT); kfeat<5>(k16, p, t2, kfT);
  __syncthreads();
  mstore(4 + wave, wave);
  __syncthreads();
  kfeat<8>(k16, p, t2, kfT); kfeat<9>(k16, p, t2, kfT);
  __syncthreads();
  mstore(8 + wave, wave);
  __syncthreads();
  kfeat<12>(k16, p, t2, kfT); kfeat<13>(k16, p, t2, kfT);
  __syncthreads();
  mstore(12 + wave, wave);
  __syncthreads();
  {  // mts 16,17 -> buffers 0,1
    float v[16];
    if (p == 0) {
      float w0 = C2 * k16[14], wm = C2 * k16[15];
      v[0] = w0 * k16[15];
#pragma unroll
      for (int j = 1; j < 16; j++) v[j] = wm * k16[j - 1];
    } else {
      v[0] = C2 * k16[15] * k16[15];
#pragma unroll
      for (int j = 1; j < 16; j++) v[j] = 0.f;
    }
    union { unsigned w[8]; u16 s[16]; } u;
#pragma unroll
    for (int j = 0; j < 8; j++) u.w[j] = pk2b(v[2 * j], v[2 * j + 1]);
#pragma unroll
    for (int el = 0; el < 16; el++) kfT[p][el][t2] = u.s[el];
  }
  __syncthreads();
  if (wave < 2) mstore(16 + wave, wave);
  for (int e = tid; e < EXPP; e += 256) {
    float s = 0.f;
    if (e == 0) s = (float)CHK;
    else if (e < 17) { float t = 0.f; for (int tt = 0; tt < CHK; tt++) t += kl[tt][e - 1]; s = 0.5f * t; }
    else if (e < EXPD) {
      int u = e - 17, i0 = u >> 4, j0 = u & 15; float t = 0.f;
      for (int tt = 0; tt < CHK; tt++) t += kl[tt][i0] * kl[tt][j0];
      s = C2 * t;
    }
    ck[(size_t)(bh * NC + c) * EXPP + e] = s;
  }
}

// Exclusive prefix over chunks (in place, bf16) on ckvT; inclusive final -> out_kv.
__global__ __launch_bounds__(256) void kv_prefix(u16* __restrict__ ckvT, const float* __restrict__ kv0,
                                                 float* __restrict__ out_kv,
                                                 float* __restrict__ ck, const float* __restrict__ k0,
                                                 float* __restrict__ out_k) {
  const int tid = threadIdx.x;
  const int bh = blockIdx.x / 10, eg = blockIdx.x % 10;
  if (eg == 9) {
    for (int e = tid; e < EXPP; e += 256) {
      float S = (e < EXPD) ? k0[(size_t)bh * EXPD + e] : 0.f;
      for (int c = 0; c < NC; c++) {
        size_t idx = ((size_t)bh * NC + c) * EXPP + e;
        float v = ck[idx];
        ck[idx] = S;
        S += v;
      }
      if (e < EXPD) out_k[(size_t)bh * EXPD + e] = S;
    }
    return;
  }
  const int hd = tid >> 2;
  const int e0 = eg * 32 + (tid & 3) * 8;
  float S[8];
#pragma unroll
  for (int j = 0; j < 8; j++) {
    int e = e0 + j;
    S[j] = (e < EXPD) ? kv0[((size_t)bh * EXPD + e) * HD + hd] : 0.f;
  }
  u16* base = ckvT + ((size_t)bh * NC * HD + hd) * EXPP + e0;
  const size_t cstride = (size_t)HD * EXPP;
  uint4 v0 = *(const uint4*)base;
  uint4 v1 = *(const uint4*)(base + cstride);
  for (int c = 0; c < NC; c++) {
    uint4 vn = v1;
    if (c + 2 < NC) vn = *(const uint4*)(base + (size_t)(c + 2) * cstride);
    union { uint4 q; unsigned w[4]; } pk;
#pragma unroll
    for (int j = 0; j < 4; j++) pk.w[j] = pk2b(S[2 * j], S[2 * j + 1]);
    *(uint4*)(base + (size_t)c * cstride) = pk.q;
    union { uint4 q; u16 s[8]; } vv; vv.q = v0;
#pragma unroll
    for (int j = 0; j < 8; j++) S[j] += b2f(vv.s[j]);
    v0 = v1; v1 = vn;
  }
#pragma unroll
  for (int j = 0; j < 8; j++) {
    int e = e0 + j;
    if (e < EXPD) out_kv[((size_t)bh * EXPD + e) * HD + hd] = S[j];
  }
}

// Per (b,h,chunk of 128): O = (Qf@S + mask_incl(poly(QK^T))@V) / den.
// R7: K-loop register-peak cut for 4 blocks/CU: bQ batch 8 -> 4 + interleaved
// group of 4 (peak fragment liveness halves), bSv 3-slot/dist-2 -> 2-slot/
// dist-1 (one KSTEP ~300cy covers the L2 read). Plain launch bounds.
__global__ __launch_bounds__(256) void out_chunk(const float* __restrict__ qkw, const u16* __restrict__ vbT,
                                                 const u16* __restrict__ ckvT, const float* __restrict__ ck,
                                                 u16* __restrict__ ob) {
  __shared__ __align__(16) u16 pool[19456];   // 38,912 B
  __shared__ float kstl[EXPP];
  __shared__ float denl[CHK];
  u16 (*qlb)[40]  = (u16(*)[40])pool;                 // 128x40, cols 16..31 zero
  u16 (*klb)[32]  = (u16(*)[32])(pool + 5120);        // 128x32, cols 16..31 zero (NaN*0 guard)
  u16 (*qfs0)[40] = (u16(*)[40])(pool + 9216);        // Qf double buffer 0
  u16 (*qfs1)[40] = (u16(*)[40])(pool + 14336);       // Qf double buffer 1
  u16 (*alB)[72]  = (u16(*)[72])pool;                 // scores s=64..127 (overlays qlb/klb)
  u16 (*alA)[72]  = (u16(*)[72])(pool + 9216);        // scores s=0..63   (overlays qfs0/qfs1)
  const int tid = threadIdx.x;
  const int bh = blockIdx.x / NC, c = blockIdx.x % NC;
  const int b = bh >> 4, h = bh & 15;
  const int wave = tid >> 6, lane = tid & 63, qd = lane >> 4, ln = lane & 15;
  const int t2 = tid >> 1, p = tid & 1;
  const size_t rowbase = (size_t)(b * SEQ + c * CHK);
  float q16[16];
  {
    const float* qp = &qkw[(rowbase + t2) * QKS + h * FEAT];
    float4 v0 = *(const float4*)qp, v1 = *(const float4*)(qp + 4);
    float4 v2 = *(const float4*)(qp + 8), v3 = *(const float4*)(qp + 12);
    q16[0] = v0.x; q16[1] = v0.y; q16[2] = v0.z; q16[3] = v0.w;
    q16[4] = v1.x; q16[5] = v1.y; q16[6] = v1.z; q16[7] = v1.w;
    q16[8] = v2.x; q16[9] = v2.y; q16[10] = v2.z; q16[11] = v2.w;
    q16[12] = v3.x; q16[13] = v3.y; q16[14] = v3.z; q16[15] = v3.w;
    unsigned qw[4];
#pragma unroll
    for (int j = 0; j < 4; j++) qw[j] = pk2b(q16[p * 8 + 2 * j], q16[p * 8 + 2 * j + 1]);
    *(uint4*)&qlb[t2][p * 8] = *(uint4*)qw;
    *(uint4*)&qlb[t2][16 + p * 8] = (uint4){0u, 0u, 0u, 0u};
    const float* kp = &qkw[(rowbase + t2) * QKS + 256 + h * FEAT + p * 8];
    float4 k0v = *(const float4*)kp, k1v = *(const float4*)(kp + 4);
    unsigned kw[4] = {pk2b(k0v.x, k0v.y), pk2b(k0v.z, k0v.w),
                      pk2b(k1v.x, k1v.y), pk2b(k1v.z, k1v.w)};
    *(uint4*)&klb[t2][p * 8] = *(uint4*)kw;
    *(uint4*)&klb[t2][16 + p * 8] = (uint4){0u, 0u, 0u, 0u};
  }
  const size_t cbase = (size_t)(bh * NC + c);
  for (int e = tid; e < EXPP; e += 256) kstl[e] = ck[cbase * EXPP + e];
  const u16* sptr = ckvT + (cbase * HD + wave * 16 + ln) * EXPP + qd * 8;
  // rolling 2-slot S-fragment buffer, prefetch distance 1 (all indices static)
  uint4 bSv[2];
  bSv[0] = *(const uint4*)(sptr + 0 * 32);
  feat_row<0>(q16, p, &qfs0[t2][p * 16]);
  f32x4 accO[8];
#pragma unroll
  for (int nt = 0; nt < 8; nt++) accO[nt] = (f32x4){0.f, 0.f, 0.f, 0.f};
  // one barrier per K-step: {barrier; prefetch S[KT+1]; bQ[0..3]; feat NXT;
  // MFMA 0..3; interleaved bQ/MFMA 4..7} — peak bQ liveness 4, not 8.
#define KSTEP(KT, CUR, NXT)                                                                \
  {                                                                                        \
    __syncthreads();                                                                       \
    if ((KT) + 1 <= 8) bSv[((KT) + 1) & 1] = *(const uint4*)(sptr + ((KT) + 1) * 32);      \
    bf16x8 bQ0[4];                                                                         \
    _Pragma("unroll")                                                                      \
    for (int nt = 0; nt < 4; nt++) bQ0[nt] = *(const bf16x8*)&CUR[nt * 16 + ln][qd * 8];   \
    feat_row<(KT) + 1>(q16, p, &NXT[t2][p * 16]);                                          \
    bf16x8 aS = *(const bf16x8*)&bSv[(KT) & 1];                                            \
    _Pragma("unroll")                                                                      \
    for (int nt = 0; nt < 4; nt++)                                                         \
      accO[nt] = __builtin_amdgcn_mfma_f32_16x16x32_bf16(aS, bQ0[nt], accO[nt], 0, 0, 0);  \
    _Pragma("unroll")                                                                      \
    for (int nt = 4; nt < 8; nt++) {                                                       \
      bf16x8 bQ1 = *(const bf16x8*)&CUR[nt * 16 + ln][qd * 8];                             \
      accO[nt] = __builtin_amdgcn_mfma_f32_16x16x32_bf16(aS, bQ1, accO[nt], 0, 0, 0);      \
    }                                                                                      \
  }
  KSTEP(0, qfs0, qfs1) KSTEP(1, qfs1, qfs0) KSTEP(2, qfs0, qfs1) KSTEP(3, qfs1, qfs0)
  KSTEP(4, qfs0, qfs1) KSTEP(5, qfs1, qfs0) KSTEP(6, qfs0, qfs1) KSTEP(7, qfs1, qfs0)
#undef KSTEP
  {  // final K-step (KT=8, buffer qfs0, aS prefetched by KSTEP(7) into bSv[0])
    __syncthreads();
    bf16x8 aS = *(const bf16x8*)&bSv[0];
#pragma unroll
    for (int nt = 0; nt < 8; nt++) {
      bf16x8 bQ = *(const bf16x8*)&qfs0[nt * 16 + ln][qd * 8];
      accO[nt] = __builtin_amdgcn_mfma_f32_16x16x32_bf16(aS, bQ, accO[nt], 0, 0, 0);
    }
  }
  __syncthreads();   // all waves done reading qfs -> alA region free
  // hoisted denominator polynomial (q16 dies here; before scores)
  float s_poly;
  {
    float s = 0.f;
#pragma unroll
    for (int i2 = 0; i2 < 8; i2++) {
      int i = p * 8 + i2;
      float inner = 0.f;
#pragma unroll
      for (int j = 0; j < 16; j++) inner += q16[j] * kstl[17 + i * 16 + j];
      s += q16[i] * inner;
    }
    s *= C2;
    float s1 = 0.f;
#pragma unroll
    for (int j2 = 0; j2 < 8; j2++) s1 += q16[p * 8 + j2] * kstl[1 + p * 8 + j2];
    s += 0.5f * s1;
    if (p == 0) s += kstl[0] + 1e-6f;
    s_poly = s;
  }
  // scores st2=0: s-tile = wave (s 0..63) -> alA. Split into 2x accU[4]
  // (alA overlays qfs only, not qlb/klb, so interleaved writes are safe).
  {
    bf16x8 aK = *(const bf16x8*)&klb[wave * 16 + ln][qd * 8];
#pragma unroll
    for (int nn = 0; nn < 2; nn++) {
      f32x4 accU[4];
#pragma unroll
      for (int j = 0; j < 4; j++) {
        bf16x8 bQ = *(const bf16x8*)&qlb[(nn * 4 + j) * 16 + ln][qd * 8];
        accU[j] = __builtin_amdgcn_mfma_f32_16x16x32_bf16(aK, bQ, (f32x4){0.f, 0.f, 0.f, 0.f}, 0, 0, 0);
      }
#pragma unroll
      for (int j = 0; j < 4; j++) {
        int t = (nn * 4 + j) * 16 + ln, sb = wave * 16 + qd * 4;
        float scm[4];
#pragma unroll
        for (int r = 0; r < 4; r++) {
          float u = accU[j][r];
          float sc = 1.f + 0.25f * u + 0.03125f * u * u;
          scm[r] = (sb + r <= t) ? sc : 0.f;
        }
        uint2 pp; pp.x = pk2b(scm[0], scm[1]); pp.y = pk2b(scm[2], scm[3]);
        *(uint2*)&alA[t][sb] = pp;
      }
    }
  }
  // scores st2=1: s-tile = wave+4 (s 64..127) -> alB (overlays qlb/klb; must
  // finish ALL reads before any write -> accU[8] held across the barrier).
  {
    f32x4 accU[8];
    bf16x8 aK = *(const bf16x8*)&klb[(wave + 4) * 16 + ln][qd * 8];
#pragma unroll
    for (int nt = 0; nt < 8; nt++) {
      bf16x8 bQ = *(const bf16x8*)&qlb[nt * 16 + ln][qd * 8];
      accU[nt] = __builtin_amdgcn_mfma_f32_16x16x32_bf16(aK, bQ, (f32x4){0.f, 0.f, 0.f, 0.f}, 0, 0, 0);
    }
    // V fragments issued here: latency hides under alB pack/write + barrier
    uint4 bVv[4];
#pragma unroll
    for (int kk2 = 0; kk2 < 4; kk2++)
      bVv[kk2] = *(const uint4*)&vbT[(size_t)(h * HD + wave * 16 + ln) * MROWS +
                                     rowbase + kk2 * 32 + qd * 8];
    __syncthreads();   // all qlb/klb reads complete before alB overwrite
#pragma unroll
    for (int nt = 0; nt < 8; nt++) {
      int t = nt * 16 + ln, sbl = wave * 16 + qd * 4;
      float scm[4];
#pragma unroll
      for (int r = 0; r < 4; r++) {
        float u = accU[nt][r];
        float sc = 1.f + 0.25f * u + 0.03125f * u * u;
        scm[r] = (64 + sbl + r <= t) ? sc : 0.f;
      }
      uint2 pp; pp.x = pk2b(scm[0], scm[1]); pp.y = pk2b(scm[2], scm[3]);
      *(uint2*)&alB[t][sbl] = pp;
    }
    __syncthreads();
    // A@V: A = V frags (registers), B = al rows
#pragma unroll
    for (int kk2 = 0; kk2 < 4; kk2++) {
      bf16x8 aV = *(const bf16x8*)&bVv[kk2];
#pragma unroll
      for (int nt = 0; nt < 8; nt++) {
        bf16x8 bA = (kk2 < 2) ? *(const bf16x8*)&alA[nt * 16 + ln][kk2 * 32 + qd * 8]
                              : *(const bf16x8*)&alB[nt * 16 + ln][(kk2 - 2) * 32 + qd * 8];
        accO[nt] = __builtin_amdgcn_mfma_f32_16x16x32_bf16(aV, bA, accO[nt], 0, 0, 0);
      }
    }
  }
  // denominator: row-sum of al + hoisted polynomial
  {
    const u16* arow = p ? &alB[t2][0] : &alA[t2][0];
    float da = 0.f;
#pragma unroll
    for (int sb = 0; sb < 8; sb++) {
      union { uint4 q; u16 hh[8]; } uu;
      uu.q = *(const uint4*)(arow + sb * 8);
#pragma unroll
      for (int j = 0; j < 8; j++) da += b2f(uu.hh[j]);
    }
    float s = s_poly + da;
    s += __shfl_xor(s, 1);
    if (p == 0) denl[t2] = s;
  }
  __syncthreads();
  // output: lane holds hd = wave*16+qd*4+r, t = nt*16+ln -> packed uint2 along hd
#pragma unroll
  for (int nt = 0; nt < 8; nt++) {
    int t = nt * 16 + ln;
    float rd = 1.0f / denl[t];
    uint2 pp;
    pp.x = pk2b(accO[nt][0] * rd, accO[nt][1] * rd);
    pp.y = pk2b(accO[nt][2] * rd, accO[nt][3] * rd);
    *(uint2*)&ob[(rowbase + t) * DM + h * HD + wave * 16 + qd * 4] = pp;
  }
}

extern "C" void kernel_launch(void* const* d_in, const int* in_sizes, int n_in,
                              void* d_out, int out_size, void* d_ws, size_t ws_size,
                              hipStream_t stream) {
  (void)in_sizes; (void)n_in; (void)out_size;
  const float* x   = (const float*)d_in[0];
  const float* kv0 = (const float*)d_in[1];
  const float* k0  = (const float*)d_in[2];
  const float* bq  = (const float*)d_in[4];
  const float* bk  = (const float*)d_in[6];
  const float* bv  = (const float*)d_in[8];
  const float* bo  = (const float*)d_in[10];
  float* out = (float*)d_out;
  char* ws = (char*)d_ws;
  size_t off = 0;
  auto take = [&](size_t bytes) { char* p = ws + off; off += (bytes + 255) & ~(size_t)255; return p; };
  u16*   xb     = (u16*)  take((size_t)BATCH * SEQ * DM * 2);
  u16*   wqkvT  = (u16*)  take((size_t)1536 * DM * 2);
  u16*   woT    = (u16*)  take((size_t)DM * DM * 2);
  float* bias_a = (float*)take((size_t)1536 * 4);
  float* qkw    = (float*)take((size_t)BATCH * SEQ * QKS * 4);
  u16*   vbT    = (u16*)  take((size_t)BATCH * SEQ * DM * 2);
  u16*   ckvT   = (u16*)  take((size_t)BH * NC * EXPP * HD * 2);
  float* ck     = (float*)take((size_t)BH * NC * EXPP * 4);
  u16*   ob     = (u16*)  take((size_t)BATCH * SEQ * DM * 2);
  if (off > ws_size) return;

  float* out_kv = out + (size_t)BATCH * SEQ * DM;
  float* out_k  = out_kv + (size_t)BH * EXPD * HD;

  prep<<<8192 + 2560 + 6, 256, 0, stream>>>(x, xb,
      (const float*)d_in[3], (const float*)d_in[5], (const float*)d_in[7], (const float*)d_in[9],
      wqkvT, woT, bq, bk, bv, bias_a);

  gemmQKV<<<dim3(8, 64), 256, 0, stream>>>(xb, wqkvT, bias_a, qkw, vbT);

  chunk_sums<<<BH * NC, 256, 0, stream>>>(qkw, vbT, ckvT, ck);
  kv_prefix<<<BH * 10, 256, 0, stream>>>(ckvT, kv0, out_kv, ck, k0, out_k);
  out_chunk<<<BH * NC, 256, 0, stream>>>(qkw, vbT, ckvT, ck, ob);

  gemm128<<<dim3(8, 64), 256, 0, stream>>>(ob, woT, bo, MROWS, DM, DM, out);
}

// Round 8
// 269.043 us; speedup vs baseline: 1.0250x; 1.0208x over previous
//
#include <hip/hip_runtime.h>

typedef unsigned short u16;
typedef __attribute__((ext_vector_type(8))) short bf16x8;
typedef __attribute__((ext_vector_type(4))) float f32x4;

#define BATCH 4
#define SEQ   2048
#define DM    1024
#define HEADS 16
#define FEAT  16
#define HD    64
#define EXPD  273
#define EXPP  288   // padded to multiple of 32 for MFMA K
#define CHK   128
#define NC    16    // SEQ / CHK
#define BH    64    // BATCH*HEADS
#define QKS   512   // fused QK projection row stride
#define MROWS 8192  // BATCH*SEQ
#define C2    0.17677669529663687f  // 1/(sqrt(2)*sqrt(16))

__device__ __forceinline__ u16 f2b(float f) {
  union { float f; unsigned u; } v; v.f = f;
  unsigned u = v.u;
  return (u16)((u + 0x7fffu + ((u >> 16) & 1u)) >> 16);
}
__device__ __forceinline__ float b2f(u16 s) {
  union { unsigned u; float f; } v; v.u = ((unsigned)s) << 16; return v.f;
}
// HW packed bf16 convert (RTNE): lo=bf16(a), hi=bf16(b) in one VALU op.
__device__ __forceinline__ unsigned pk2b(float a, float b) {
  unsigned r;
  asm("v_cvt_pk_bf16_f32 %0, %1, %2" : "=v"(r) : "v"(a), "v"(b));
  return r;
}

typedef const unsigned int __attribute__((address_space(1)))* gas1;
typedef unsigned int __attribute__((address_space(3)))* las3;
__device__ __forceinline__ void gl_lds16(const u16* g, u16* l) {
  __builtin_amdgcn_global_load_lds((gas1)(const void*)g, (las3)(void*)l, 16, 0, 0);
}

// Fused prep: x->bf16 (0..8191), weight cast-transposes (8192..10751), bias concat (10752..10757)
__global__ __launch_bounds__(256) void prep(const float* __restrict__ x, u16* __restrict__ xb,
                                            const float* __restrict__ Wq, const float* __restrict__ Wk,
                                            const float* __restrict__ Wv, const float* __restrict__ Wo,
                                            u16* __restrict__ wqkvT, u16* __restrict__ woT,
                                            const float* __restrict__ bq, const float* __restrict__ bk,
                                            const float* __restrict__ bv, float* __restrict__ bias_all) {
  __shared__ float tile[32][33];
  int id = blockIdx.x;
  if (id < 8192) {
    int i = id * 256 + threadIdx.x;
    float4 v = ((const float4*)x)[i];
    uint2 r; r.x = pk2b(v.x, v.y); r.y = pk2b(v.z, v.w);
    ((uint2*)xb)[i] = r;
    return;
  }
  id -= 8192;
  if (id < 2560) {
    const float* src; u16* dst; int N, t;
    if (id < 256)       { src = Wq; dst = wqkvT;            N = 256;  t = id; }
    else if (id < 512)  { src = Wk; dst = wqkvT + 256 * DM; N = 256;  t = id - 256; }
    else if (id < 1536) { src = Wv; dst = wqkvT + 512 * DM; N = 1024; t = id - 512; }
    else                { src = Wo; dst = woT;              N = 1024; t = id - 1536; }
    int nt = N / 32;
    int n0 = (t % nt) * 32, k0 = (t / nt) * 32;
    int tx = threadIdx.x & 31, ty = threadIdx.x >> 5;
    for (int i = ty; i < 32; i += 8)
      tile[i][tx] = src[(size_t)(k0 + i) * N + n0 + tx];
    __syncthreads();
    for (int i = ty; i < 32; i += 8)
      dst[(size_t)(n0 + i) * DM + k0 + tx] = f2b(tile[tx][i]);
    return;
  }
  id -= 2560;
  int i = id * 256 + threadIdx.x;  // 0..1535
  float v;
  if (i < 256) v = bq[i];
  else if (i < 512) v = bk[i - 256];
  else v = bv[i - 512];
  bias_all[i] = v;
}

// Fused QKV projection: C = xb @ wqkvT^T + bias_all. N=1536.
// Tile 128x192 (grid 8x64 = 512 blocks = 2/CU balanced), per-wave 64x96 (acc 4x6).
// Double-buffered LDS, counted vmcnt(5), raw s_barrier, XOR chunk swizzle.
__global__ __launch_bounds__(256, 2) void gemmQKV(const u16* __restrict__ A, const u16* __restrict__ BT,
                                                  const float* __restrict__ bias,
                                                  float* __restrict__ qkw, u16* __restrict__ vbT) {
  __shared__ __align__(16) u16 As[2][128 * 32];
  __shared__ __align__(16) u16 Bs[2][192 * 32];
  const int tid = threadIdx.x;
  const int wave = tid >> 6, lane = tid & 63, qd = lane >> 4, ln = lane & 15;
  const int wr = (wave >> 1) * 64, wc = (wave & 1) * 96;
  const int m0 = blockIdx.y * 128, n0 = blockIdx.x * 192;
  const int K = DM;
  f32x4 acc[4][6];
#pragma unroll
  for (int i = 0; i < 4; i++)
#pragma unroll
    for (int j = 0; j < 6; j++) acc[i][j] = (f32x4){0.f, 0.f, 0.f, 0.f};
  const int sr = tid >> 2;
  const int scs = (((tid & 3) ^ ((sr >> 1) & 3))) * 8;   // u16 offset of swizzled source chunk
  const u16* gA0 = A + (size_t)(m0 + sr) * K + scs;
  const u16* gA1 = gA0 + (size_t)64 * K;
  const u16* gB0 = BT + (size_t)(n0 + sr) * K + scs;
  auto stage = [&](int buf, int kk) {
    gl_lds16(gA0 + kk, &As[buf][wave * 512]);
    gl_lds16(gA1 + kk, &As[buf][2048 + wave * 512]);
    gl_lds16(gB0 + kk,                   &Bs[buf][wave * 512]);
    gl_lds16(gB0 + (size_t)64 * K + kk,  &Bs[buf][2048 + wave * 512]);
    gl_lds16(gB0 + (size_t)128 * K + kk, &Bs[buf][4096 + wave * 512]);
  };
  const int swz = ((ln >> 1) & 3) << 3;
  auto compute = [&](int buf) {
    bf16x8 af[4], bf[6];
#pragma unroll
    for (int t = 0; t < 4; t++)
      af[t] = *(const bf16x8*)&As[buf][(wr + t * 16 + ln) * 32 + ((qd * 8) ^ swz)];
#pragma unroll
    for (int u = 0; u < 6; u++)
      bf[u] = *(const bf16x8*)&Bs[buf][(wc + u * 16 + ln) * 32 + ((qd * 8) ^ swz)];
#pragma unroll
    for (int mt = 0; mt < 4; mt++)
#pragma unroll
      for (int nt = 0; nt < 6; nt++)
        acc[mt][nt] = __builtin_amdgcn_mfma_f32_16x16x32_bf16(af[mt], bf[nt], acc[mt][nt], 0, 0, 0);
  };
  stage(0, 0);
  int buf = 0;
  for (int kk = 32; kk < K; kk += 32) {
    stage(buf ^ 1, kk);
    asm volatile("s_waitcnt vmcnt(5)" ::: "memory");
    __builtin_amdgcn_s_barrier();
    asm volatile("" ::: "memory");
    compute(buf);
    asm volatile("" ::: "memory");
    __builtin_amdgcn_s_barrier();
    buf ^= 1;
  }
  asm volatile("s_waitcnt vmcnt(0)" ::: "memory");
  __builtin_amdgcn_s_barrier();
  asm volatile("" ::: "memory");
  compute(buf);
#pragma unroll
  for (int nt = 0; nt < 6; nt++) {
    int col = n0 + wc + nt * 16 + ln;
    float bv = bias[col];
    if (col < 512) {
#pragma unroll
      for (int mt = 0; mt < 4; mt++)
#pragma unroll
        for (int r = 0; r < 4; r++) {
          int row = m0 + wr + mt * 16 + qd * 4 + r;
          qkw[(size_t)row * QKS + col] = acc[mt][nt][r] + bv;
        }
    } else {
      int vcol = col - 512;
#pragma unroll
      for (int mt = 0; mt < 4; mt++) {
        uint2 pp;
        pp.x = pk2b(acc[mt][nt][0] + bv, acc[mt][nt][1] + bv);
        pp.y = pk2b(acc[mt][nt][2] + bv, acc[mt][nt][3] + bv);
        int row0 = m0 + wr + mt * 16 + qd * 4;
        *(uint2*)&vbT[(size_t)vcol * MROWS + row0] = pp;
      }
    }
  }
}

// C = A(MxK bf16 rm) @ BT^T + bias -> fp32 rm (O projection).
__global__ __launch_bounds__(256, 3) void gemm128(const u16* __restrict__ A, const u16* __restrict__ BT,
                                                  const float* __restrict__ bias, int M, int N, int K,
                                                  float* __restrict__ outF) {
  __shared__ __align__(16) u16 As[2][128 * 32];
  __shared__ __align__(16) u16 Bs[2][128 * 32];
  const int tid = threadIdx.x;
  const int wave = tid >> 6, lane = tid & 63, qd = lane >> 4, ln = lane & 15;
  const int wr = (wave >> 1) * 64, wc = (wave & 1) * 64;
  const int m0 = blockIdx.y * 128, n0 = blockIdx.x * 128;
  f32x4 acc[4][4];
#pragma unroll
  for (int i = 0; i < 4; i++)
#pragma unroll
    for (int j = 0; j < 4; j++) acc[i][j] = (f32x4){0.f, 0.f, 0.f, 0.f};
  const int sr = tid >> 2;
  const int scs = (((tid & 3) ^ ((sr >> 1) & 3))) * 8;
  const u16* gA0 = A + (size_t)(m0 + sr) * K + scs;
  const u16* gA1 = gA0 + (size_t)64 * K;
  const u16* gB0 = BT + (size_t)(n0 + sr) * K + scs;
  const u16* gB1 = gB0 + (size_t)64 * K;
  auto stage = [&](int buf, int kk) {
    gl_lds16(gA0 + kk, &As[buf][wave * 512]);
    gl_lds16(gA1 + kk, &As[buf][2048 + wave * 512]);
    gl_lds16(gB0 + kk, &Bs[buf][wave * 512]);
    gl_lds16(gB1 + kk, &Bs[buf][2048 + wave * 512]);
  };
  const int swz = ((ln >> 1) & 3) << 3;
  auto compute = [&](int buf) {
    bf16x8 af[4], bf[4];
#pragma unroll
    for (int t = 0; t < 4; t++)
      af[t] = *(const bf16x8*)&As[buf][(wr + t * 16 + ln) * 32 + ((qd * 8) ^ swz)];
#pragma unroll
    for (int u = 0; u < 4; u++)
      bf[u] = *(const bf16x8*)&Bs[buf][(wc + u * 16 + ln) * 32 + ((qd * 8) ^ swz)];
#pragma unroll
    for (int mt = 0; mt < 4; mt++)
#pragma unroll
      for (int nt = 0; nt < 4; nt++)
        acc[mt][nt] = __builtin_amdgcn_mfma_f32_16x16x32_bf16(af[mt], bf[nt], acc[mt][nt], 0, 0, 0);
  };
  stage(0, 0);
  int buf = 0;
  for (int kk = 32; kk < K; kk += 32) {
    stage(buf ^ 1, kk);
    asm volatile("s_waitcnt vmcnt(4)" ::: "memory");
    __builtin_amdgcn_s_barrier();
    asm volatile("" ::: "memory");
    compute(buf);
    asm volatile("" ::: "memory");
    __builtin_amdgcn_s_barrier();
    buf ^= 1;
  }
  asm volatile("s_waitcnt vmcnt(0)" ::: "memory");
  __builtin_amdgcn_s_barrier();
  asm volatile("" ::: "memory");
  compute(buf);
#pragma unroll
  for (int nt = 0; nt < 4; nt++) {
    int col = n0 + wc + nt * 16 + ln;
    float bv = bias[col];
#pragma unroll
    for (int mt = 0; mt < 4; mt++)
#pragma unroll
      for (int r = 0; r < 4; r++) {
        int row = m0 + wr + mt * 16 + qd * 4 + r;
        outF[(size_t)row * N + col] = acc[mt][nt][r] + bv;
      }
  }
}

// Register-q featurize of a 32-el chunk (e = 32*KT + 16*p .. +15) into dst (contiguous 16 u16).
template<int KT>
__device__ __forceinline__ void feat_row(const float* q16, int p, u16* dst) {
  float v[16];
  if (KT == 0 && p == 0) {
    v[0] = 1.0f;
#pragma unroll
    for (int j = 1; j < 16; j++) v[j] = 0.5f * q16[j - 1];
  } else if (KT == 0) {  // p==1: e=16..31
    v[0] = 0.5f * q16[15];
    float wm = C2 * q16[0];
#pragma unroll
    for (int j = 1; j < 16; j++) v[j] = wm * q16[j - 1];
  } else {
    constexpr int c = 2 * KT;
    float wm = C2 * (p ? q16[c]     : q16[c - 1]);
    float w0 = C2 * (p ? q16[c - 1] : q16[c - 2]);
    v[0] = w0 * q16[15];
#pragma unroll
    for (int j = 1; j < 16; j++) v[j] = wm * q16[j - 1];
    if (KT == 8 && p) {  // e >= 273 -> 0
#pragma unroll
      for (int j = 1; j < 16; j++) v[j] = 0.f;
    }
  }
  unsigned w[8];
#pragma unroll
  for (int j = 0; j < 8; j++) w[j] = pk2b(v[2 * j], v[2 * j + 1]);
  *(uint4*)dst = *(uint4*)w;
  *(uint4*)(dst + 8) = *(uint4*)(w + 4);
}

// Register-k featurize for chunk_sums: mt = MTB + 2p -> buffer (mt & 3), [el][t] layout
template<int MTB>
__device__ __forceinline__ void kfeat(const float* k16, int p, int t2, u16 (*kfT)[16][136]) {
  float v[16];
  if (MTB == 0) {
    if (p == 0) {
      v[0] = 1.0f;
#pragma unroll
      for (int j = 1; j < 16; j++) v[j] = 0.5f * k16[j - 1];
    } else {
      float w0 = C2 * k16[0], wm = C2 * k16[1];
      v[0] = w0 * k16[15];
#pragma unroll
      for (int j = 1; j < 16; j++) v[j] = wm * k16[j - 1];
    }
  } else if (MTB == 1) {
    if (p == 0) {
      v[0] = 0.5f * k16[15];
      float wm = C2 * k16[0];
#pragma unroll
      for (int j = 1; j < 16; j++) v[j] = wm * k16[j - 1];
    } else {
      float w0 = C2 * k16[1], wm = C2 * k16[2];
      v[0] = w0 * k16[15];
#pragma unroll
      for (int j = 1; j < 16; j++) v[j] = wm * k16[j - 1];
    }
  } else {
    float wm = C2 * (p ? k16[MTB + 1] : k16[MTB - 1]);
    float w0 = C2 * (p ? k16[MTB]     : k16[MTB - 2]);
    v[0] = w0 * k16[15];
#pragma unroll
    for (int j = 1; j < 16; j++) v[j] = wm * k16[j - 1];
  }
  union { unsigned w[8]; u16 s[16]; } u;
#pragma unroll
  for (int j = 0; j < 8; j++) u.w[j] = pk2b(v[2 * j], v[2 * j + 1]);
  int b = 2 * p + (MTB & 1);
#pragma unroll
  for (int el = 0; el < 16; el++) kfT[b][el][t2] = u.s[el];
}

// Per (b,h,chunk of 128): ckvT[hd][e] = sum_t Kf[t][e]*V[t][hd] (bf16), ck[e] = colsum Kf (fp32)
__global__ __launch_bounds__(256) void chunk_sums(const float* __restrict__ qkw, const u16* __restrict__ vbT,
                                                  u16* __restrict__ ckvT, float* __restrict__ ck) {
  __shared__ float kl[CHK][20];
  __shared__ __align__(16) u16 kfT[4][16][136];
  const int tid = threadIdx.x;
  const int bh = blockIdx.x / NC, c = blockIdx.x % NC;
  const int b = bh >> 4, h = bh & 15;
  const int wave = tid >> 6, lane = tid & 63, qd = lane >> 4, ln = lane & 15;
  const int t2 = tid >> 1, p = tid & 1;
  const size_t rowbase = (size_t)(b * SEQ + c * CHK);
  float k16[16];
  {
    const float* kp = &qkw[(rowbase + t2) * QKS + 256 + h * FEAT];
    float4 v0 = *(const float4*)kp, v1 = *(const float4*)(kp + 4);
    float4 v2 = *(const float4*)(kp + 8), v3 = *(const float4*)(kp + 12);
    k16[0] = v0.x; k16[1] = v0.y; k16[2] = v0.z; k16[3] = v0.w;
    k16[4] = v1.x; k16[5] = v1.y; k16[6] = v1.z; k16[7] = v1.w;
    k16[8] = v2.x; k16[9] = v2.y; k16[10] = v2.z; k16[11] = v2.w;
    k16[12] = v3.x; k16[13] = v3.y; k16[14] = v3.z; k16[15] = v3.w;
    float4 h0, h1;
    if (p == 0) { h0 = v0; h1 = v1; } else { h0 = v2; h1 = v3; }
    *(float4*)&kl[t2][p * 8] = h0;
    *(float4*)&kl[t2][p * 8 + 4] = h1;
  }
  uint4 bVv[4][4];
#pragma unroll
  for (int kk2 = 0; kk2 < 4; kk2++)
#pragma unroll
    for (int nt = 0; nt < 4; nt++)
      bVv[kk2][nt] = *(const uint4*)&vbT[(size_t)(h * HD + nt * 16 + ln) * MROWS +
                                         rowbase + kk2 * 32 + qd * 8];
  const size_t obase = (size_t)(bh * NC + c) * HD;
  auto mstore = [&](int mt, int bufw) {
    f32x4 acc[4];
#pragma unroll
    for (int nt = 0; nt < 4; nt++) acc[nt] = (f32x4){0.f, 0.f, 0.f, 0.f};
#pragma unroll
    for (int kk2 = 0; kk2 < 4; kk2++) {
      bf16x8 a = *(const bf16x8*)&kfT[bufw][ln][kk2 * 32 + qd * 8];
#pragma unroll
      for (int nt = 0; nt < 4; nt++) {
        bf16x8 bb = *(const bf16x8*)&bVv[kk2][nt];
        acc[nt] = __builtin_amdgcn_mfma_f32_16x16x32_bf16(a, bb, acc[nt], 0, 0, 0);
      }
    }
#pragma unroll
    for (int nt = 0; nt < 4; nt++) {
      uint2 pp;
      pp.x = pk2b(acc[nt][0], acc[nt][1]);
      pp.y = pk2b(acc[nt][2], acc[nt][3]);
      *(uint2*)&ckvT[(obase + nt * 16 + ln) * EXPP + mt * 16 + qd * 4] = pp;
    }
  };
  __syncthreads();
  kfeat<0>(k16, p, t2, kfT); kfeat<1>(k16, p, t2, kfT);
  __syncthreads();
  mstore(wave, wave);
  __syncthreads();
  kfeat<4>(k16, p, t2, kfT); kfeat<5>(k16, p, t2, kfT);
  __syncthreads();
  mstore(4 + wave, wave);
  __syncthreads();
  kfeat<8>(k16, p, t2, kfT); kfeat<9>(k16, p, t2, kfT);
  __syncthreads();
  mstore(8 + wave, wave);
  __syncthreads();
  kfeat<12>(k16, p, t2, kfT); kfeat<13>(k16, p, t2, kfT);
  __syncthreads();
  mstore(12 + wave, wave);
  __syncthreads();
  {  // mts 16,17 -> buffers 0,1
    float v[16];
    if (p == 0) {
      float w0 = C2 * k16[14], wm = C2 * k16[15];
      v[0] = w0 * k16[15];
#pragma unroll
      for (int j = 1; j < 16; j++) v[j] = wm * k16[j - 1];
    } else {
      v[0] = C2 * k16[15] * k16[15];
#pragma unroll
      for (int j = 1; j < 16; j++) v[j] = 0.f;
    }
    union { unsigned w[8]; u16 s[16]; } u;
#pragma unroll
    for (int j = 0; j < 8; j++) u.w[j] = pk2b(v[2 * j], v[2 * j + 1]);
#pragma unroll
    for (int el = 0; el < 16; el++) kfT[p][el][t2] = u.s[el];
  }
  __syncthreads();
  if (wave < 2) mstore(16 + wave, wave);
  for (int e = tid; e < EXPP; e += 256) {
    float s = 0.f;
    if (e == 0) s = (float)CHK;
    else if (e < 17) { float t = 0.f; for (int tt = 0; tt < CHK; tt++) t += kl[tt][e - 1]; s = 0.5f * t; }
    else if (e < EXPD) {
      int u = e - 17, i0 = u >> 4, j0 = u & 15; float t = 0.f;
      for (int tt = 0; tt < CHK; tt++) t += kl[tt][i0] * kl[tt][j0];
      s = C2 * t;
    }
    ck[(size_t)(bh * NC + c) * EXPP + e] = s;
  }
}

// Exclusive prefix over chunks (in place, bf16) on ckvT; inclusive final -> out_kv.
__global__ __launch_bounds__(256) void kv_prefix(u16* __restrict__ ckvT, const float* __restrict__ kv0,
                                                 float* __restrict__ out_kv,
                                                 float* __restrict__ ck, const float* __restrict__ k0,
                                                 float* __restrict__ out_k) {
  const int tid = threadIdx.x;
  const int bh = blockIdx.x / 10, eg = blockIdx.x % 10;
  if (eg == 9) {
    for (int e = tid; e < EXPP; e += 256) {
      float S = (e < EXPD) ? k0[(size_t)bh * EXPD + e] : 0.f;
      for (int c = 0; c < NC; c++) {
        size_t idx = ((size_t)bh * NC + c) * EXPP + e;
        float v = ck[idx];
        ck[idx] = S;
        S += v;
      }
      if (e < EXPD) out_k[(size_t)bh * EXPD + e] = S;
    }
    return;
  }
  const int hd = tid >> 2;
  const int e0 = eg * 32 + (tid & 3) * 8;
  float S[8];
#pragma unroll
  for (int j = 0; j < 8; j++) {
    int e = e0 + j;
    S[j] = (e < EXPD) ? kv0[((size_t)bh * EXPD + e) * HD + hd] : 0.f;
  }
  u16* base = ckvT + ((size_t)bh * NC * HD + hd) * EXPP + e0;
  const size_t cstride = (size_t)HD * EXPP;
  uint4 v0 = *(const uint4*)base;
  uint4 v1 = *(const uint4*)(base + cstride);
  for (int c = 0; c < NC; c++) {
    uint4 vn = v1;
    if (c + 2 < NC) vn = *(const uint4*)(base + (size_t)(c + 2) * cstride);
    union { uint4 q; unsigned w[4]; } pk;
#pragma unroll
    for (int j = 0; j < 4; j++) pk.w[j] = pk2b(S[2 * j], S[2 * j + 1]);
    *(uint4*)(base + (size_t)c * cstride) = pk.q;
    union { uint4 q; u16 s[8]; } vv; vv.q = v0;
#pragma unroll
    for (int j = 0; j < 8; j++) S[j] += b2f(vv.s[j]);
    v0 = v1; v1 = vn;
  }
#pragma unroll
  for (int j = 0; j < 8; j++) {
    int e = e0 + j;
    if (e < EXPD) out_kv[((size_t)bh * EXPD + e) * HD + hd] = S[j];
  }
}

// Per (b,h,chunk of 128): O = (Qf@S + mask_incl(poly(QK^T))@V) / den.
// R8: quad-buffered Qf -> 2 chunks per barrier (K-loop barriers 10 -> 5,
// total 13 -> 9). LDS space bought via shared 16B zero-slab: qlb/klb shrink
// to [128][16]; lanes with qd>=2 read the zero slab (per-lane LDS addressing,
// broadcast = free). Pool 51,200B, total ~53KB -> still 3 blocks/CU.
// T5 setprio(1) wraps every MFMA cluster (3 indep blocks/CU = attn-like regime).
__global__ __launch_bounds__(256) void out_chunk(const float* __restrict__ qkw, const u16* __restrict__ vbT,
                                                 const u16* __restrict__ ckvT, const float* __restrict__ ck,
                                                 u16* __restrict__ ob) {
  __shared__ __align__(16) u16 pool[25600];   // 51,200 B
  __shared__ float kstl[EXPP];
  __shared__ float denl[CHK];
  u16 (*qlb)[16] = (u16(*)[16])pool;                  // 128x16 (no zero half)
  u16 (*klb)[16] = (u16(*)[16])(pool + 2048);         // 128x16 (no zero half)
  u16* zslab     = pool + 4096;                       // 8 u16 shared zeros (16B)
  u16 (*qf0)[40] = (u16(*)[40])(pool + 4104);         // Qf quad buffers
  u16 (*qf1)[40] = (u16(*)[40])(pool + 9224);
  u16 (*qf2)[40] = (u16(*)[40])(pool + 14344);
  u16 (*qf3)[40] = (u16(*)[40])(pool + 19464);        // ends 24,584
  u16 (*alB)[72] = (u16(*)[72])pool;                  // scores s=64..127 (overlays qlb/klb/zslab/qf0-head)
  u16 (*alA)[72] = (u16(*)[72])(pool + 9216);         // scores s=0..63   (overlays qf1/qf2-head)
  const int tid = threadIdx.x;
  const int bh = blockIdx.x / NC, c = blockIdx.x % NC;
  const int b = bh >> 4, h = bh & 15;
  const int wave = tid >> 6, lane = tid & 63, qd = lane >> 4, ln = lane & 15;
  const int t2 = tid >> 1, p = tid & 1;
  const size_t rowbase = (size_t)(b * SEQ + c * CHK);
  float q16[16];
  {
    const float* qp = &qkw[(rowbase + t2) * QKS + h * FEAT];
    float4 v0 = *(const float4*)qp, v1 = *(const float4*)(qp + 4);
    float4 v2 = *(const float4*)(qp + 8), v3 = *(const float4*)(qp + 12);
    q16[0] = v0.x; q16[1] = v0.y; q16[2] = v0.z; q16[3] = v0.w;
    q16[4] = v1.x; q16[5] = v1.y; q16[6] = v1.z; q16[7] = v1.w;
    q16[8] = v2.x; q16[9] = v2.y; q16[10] = v2.z; q16[11] = v2.w;
    q16[12] = v3.x; q16[13] = v3.y; q16[14] = v3.z; q16[15] = v3.w;
    unsigned qw[4];
#pragma unroll
    for (int j = 0; j < 4; j++) qw[j] = pk2b(q16[p * 8 + 2 * j], q16[p * 8 + 2 * j + 1]);
    *(uint4*)&qlb[t2][p * 8] = *(uint4*)qw;
    const float* kp = &qkw[(rowbase + t2) * QKS + 256 + h * FEAT + p * 8];
    float4 k0v = *(const float4*)kp, k1v = *(const float4*)(kp + 4);
    unsigned kw[4] = {pk2b(k0v.x, k0v.y), pk2b(k0v.z, k0v.w),
                      pk2b(k1v.x, k1v.y), pk2b(k1v.z, k1v.w)};
    *(uint4*)&klb[t2][p * 8] = *(uint4*)kw;
    if (tid == 0) *(uint4*)zslab = (uint4){0u, 0u, 0u, 0u};
  }
  const size_t cbase = (size_t)(bh * NC + c);
  for (int e = tid; e < EXPP; e += 256) kstl[e] = ck[cbase * EXPP + e];
  const u16* sptr = ckvT + (cbase * HD + wave * 16 + ln) * EXPP + qd * 8;
  // 4-slot rolling S-fragment buffer: slot = kt & 3; pairs prefetched 1 phase ahead
  uint4 bSv[4];
  bSv[0] = *(const uint4*)(sptr + 0 * 32);
  bSv[1] = *(const uint4*)(sptr + 1 * 32);
  feat_row<0>(q16, p, &qf0[t2][p * 16]);
  feat_row<1>(q16, p, &qf1[t2][p * 16]);
  f32x4 accO[8];
#pragma unroll
  for (int nt = 0; nt < 8; nt++) accO[nt] = (f32x4){0.f, 0.f, 0.f, 0.f};
  // per chunk: 4+4 bQ sub-batched MFMA (R7 style), setprio around MFMA
#define CHUNK(KT, QF)                                                                      \
  {                                                                                        \
    bf16x8 aS = *(const bf16x8*)&bSv[(KT) & 3];                                            \
    bf16x8 bq0[4];                                                                         \
    _Pragma("unroll")                                                                      \
    for (int nt = 0; nt < 4; nt++) bq0[nt] = *(const bf16x8*)&QF[nt * 16 + ln][qd * 8];    \
    __builtin_amdgcn_s_setprio(1);                                                         \
    _Pragma("unroll")                                                                      \
    for (int nt = 0; nt < 4; nt++)                                                         \
      accO[nt] = __builtin_amdgcn_mfma_f32_16x16x32_bf16(aS, bq0[nt], accO[nt], 0, 0, 0);  \
    _Pragma("unroll")                                                                      \
    for (int nt = 4; nt < 8; nt++) {                                                       \
      bf16x8 bq1 = *(const bf16x8*)&QF[nt * 16 + ln][qd * 8];                              \
      accO[nt] = __builtin_amdgcn_mfma_f32_16x16x32_bf16(aS, bq1, accO[nt], 0, 0, 0);      \
    }                                                                                      \
    __builtin_amdgcn_s_setprio(0);                                                         \
  }
  // PH0: chunks 0,1 (qf0,qf1); prefetch S2,S3; feat 2,3 -> qf2,qf3
  __syncthreads();
  bSv[2] = *(const uint4*)(sptr + 2 * 32);
  bSv[3] = *(const uint4*)(sptr + 3 * 32);
  CHUNK(0, qf0)
  feat_row<2>(q16, p, &qf2[t2][p * 16]);
  CHUNK(1, qf1)
  feat_row<3>(q16, p, &qf3[t2][p * 16]);
  // PH1: chunks 2,3 (qf2,qf3); prefetch S4,S5; feat 4,5 -> qf0,qf1
  __syncthreads();
  bSv[0] = *(const uint4*)(sptr + 4 * 32);
  bSv[1] = *(const uint4*)(sptr + 5 * 32);
  CHUNK(2, qf2)
  feat_row<4>(q16, p, &qf0[t2][p * 16]);
  CHUNK(3, qf3)
  feat_row<5>(q16, p, &qf1[t2][p * 16]);
  // PH2: chunks 4,5 (qf0,qf1); prefetch S6,S7; feat 6,7 -> qf2,qf3
  __syncthreads();
  bSv[2] = *(const uint4*)(sptr + 6 * 32);
  bSv[3] = *(const uint4*)(sptr + 7 * 32);
  CHUNK(4, qf0)
  feat_row<6>(q16, p, &qf2[t2][p * 16]);
  CHUNK(5, qf1)
  feat_row<7>(q16, p, &qf3[t2][p * 16]);
  // PH3: chunks 6,7 (qf2,qf3); prefetch S8 -> slot 0; feat 8 -> qf0
  __syncthreads();
  bSv[0] = *(const uint4*)(sptr + 8 * 32);
  CHUNK(6, qf2)
  feat_row<8>(q16, p, &qf0[t2][p * 16]);
  CHUNK(7, qf3)
  // FIN: chunk 8 (qf0), aS = bSv[8&3=0]
  __syncthreads();
  CHUNK(8, qf0)
#undef CHUNK
  __syncthreads();   // all waves done reading qf buffers -> alA region free
  // hoisted denominator polynomial (q16 dies here; before scores)
  float s_poly;
  {
    float s = 0.f;
#pragma unroll
    for (int i2 = 0; i2 < 8; i2++) {
      int i = p * 8 + i2;
      float inner = 0.f;
#pragma unroll
      for (int j = 0; j < 16; j++) inner += q16[j] * kstl[17 + i * 16 + j];
      s += q16[i] * inner;
    }
    s *= C2;
    float s1 = 0.f;
#pragma unroll
    for (int j2 = 0; j2 < 8; j2++) s1 += q16[p * 8 + j2] * kstl[1 + p * 8 + j2];
    s += 0.5f * s1;
    if (p == 0) s += kstl[0] + 1e-6f;
    s_poly = s;
  }
  // scores st2=0: s-tile = wave (s 0..63) -> alA. K=32 MFMA with zero-slab for
  // the k>=16 half: lanes qd>=2 read the shared 16B zero row (broadcast, free).
  {
    const u16* kap = (qd < 2) ? &klb[wave * 16 + ln][qd * 8] : zslab;
    bf16x8 aK = *(const bf16x8*)kap;
#pragma unroll
    for (int nn = 0; nn < 2; nn++) {
      f32x4 accU[4];
      __builtin_amdgcn_s_setprio(1);
#pragma unroll
      for (int j = 0; j < 4; j++) {
        const u16* qap = (qd < 2) ? &qlb[(nn * 4 + j) * 16 + ln][qd * 8] : zslab;
        bf16x8 bQ = *(const bf16x8*)qap;
        accU[j] = __builtin_amdgcn_mfma_f32_16x16x32_bf16(aK, bQ, (f32x4){0.f, 0.f, 0.f, 0.f}, 0, 0, 0);
      }
      __builtin_amdgcn_s_setprio(0);
#pragma unroll
      for (int j = 0; j < 4; j++) {
        int t = (nn * 4 + j) * 16 + ln, sb = wave * 16 + qd * 4;
        float scm[4];
#pragma unroll
        for (int r = 0; r < 4; r++) {
          float u = accU[j][r];
          float sc = 1.f + 0.25f * u + 0.03125f * u * u;
          scm[r] = (sb + r <= t) ? sc : 0.f;
        }
        uint2 pp; pp.x = pk2b(scm[0], scm[1]); pp.y = pk2b(scm[2], scm[3]);
        *(uint2*)&alA[t][sb] = pp;
      }
    }
  }
  // scores st2=1: s-tile = wave+4 (s 64..127) -> alB (overlays qlb/klb; must
  // finish ALL reads before any write -> accU[8] held across the barrier).
  {
    f32x4 accU[8];
    const u16* kap = (qd < 2) ? &klb[(wave + 4) * 16 + ln][qd * 8] : zslab;
    bf16x8 aK = *(const bf16x8*)kap;
    __builtin_amdgcn_s_setprio(1);
#pragma unroll
    for (int nt = 0; nt < 8; nt++) {
      const u16* qap = (qd < 2) ? &qlb[nt * 16 + ln][qd * 8] : zslab;
      bf16x8 bQ = *(const bf16x8*)qap;
      accU[nt] = __builtin_amdgcn_mfma_f32_16x16x32_bf16(aK, bQ, (f32x4){0.f, 0.f, 0.f, 0.f}, 0, 0, 0);
    }
    __builtin_amdgcn_s_setprio(0);
    // V fragments issued here: latency hides under alB pack/write + barrier
    uint4 bVv[4];
#pragma unroll
    for (int kk2 = 0; kk2 < 4; kk2++)
      bVv[kk2] = *(const uint4*)&vbT[(size_t)(h * HD + wave * 16 + ln) * MROWS +
                                     rowbase + kk2 * 32 + qd * 8];
    __syncthreads();   // all qlb/klb/zslab reads complete before alB overwrite
#pragma unroll
    for (int nt = 0; nt < 8; nt++) {
      int t = nt * 16 + ln, sbl = wave * 16 + qd * 4;
      float scm[4];
#pragma unroll
      for (int r = 0; r < 4; r++) {
        float u = accU[nt][r];
        float sc = 1.f + 0.25f * u + 0.03125f * u * u;
        scm[r] = (64 + sbl + r <= t) ? sc : 0.f;
      }
      uint2 pp; pp.x = pk2b(scm[0], scm[1]); pp.y = pk2b(scm[2], scm[3]);
      *(uint2*)&alB[t][sbl] = pp;
    }
    __syncthreads();
    // A@V: A = V frags (registers), B = al rows
    __builtin_amdgcn_s_setprio(1);
#pragma unroll
    for (int kk2 = 0; kk2 < 4; kk2++) {
      bf16x8 aV = *(const bf16x8*)&bVv[kk2];
#pragma unroll
      for (int nt = 0; nt < 8; nt++) {
        bf16x8 bA = (kk2 < 2) ? *(const bf16x8*)&alA[nt * 16 + ln][kk2 * 32 + qd * 8]
                              : *(const bf16x8*)&alB[nt * 16 + ln][(kk2 - 2) * 32 + qd * 8];
        accO[nt] = __builtin_amdgcn_mfma_f32_16x16x32_bf16(aV, bA, accO[nt], 0, 0, 0);
      }
    }
    __builtin_amdgcn_s_setprio(0);
  }
  // denominator: row-sum of al + hoisted polynomial
  {
    const u16* arow = p ? &alB[t2][0] : &alA[t2][0];
    float da = 0.f;
#pragma unroll
    for (int sb = 0; sb < 8; sb++) {
      union { uint4 q; u16 hh[8]; } uu;
      uu.q = *(const uint4*)(arow + sb * 8);
#pragma unroll
      for (int j = 0; j < 8; j++) da += b2f(uu.hh[j]);
    }
    float s = s_poly + da;
    s += __shfl_xor(s, 1);
    if (p == 0) denl[t2] = s;
  }
  __syncthreads();
  // output: lane holds hd = wave*16+qd*4+r, t = nt*16+ln -> packed uint2 along hd
#pragma unroll
  for (int nt = 0; nt < 8; nt++) {
    int t = nt * 16 + ln;
    float rd = 1.0f / denl[t];
    uint2 pp;
    pp.x = pk2b(accO[nt][0] * rd, accO[nt][1] * rd);
    pp.y = pk2b(accO[nt][2] * rd, accO[nt][3] * rd);
    *(uint2*)&ob[(rowbase + t) * DM + h * HD + wave * 16 + qd * 4] = pp;
  }
}

extern "C" void kernel_launch(void* const* d_in, const int* in_sizes, int n_in,
                              void* d_out, int out_size, void* d_ws, size_t ws_size,
                              hipStream_t stream) {
  (void)in_sizes; (void)n_in; (void)out_size;
  const float* x   = (const float*)d_in[0];
  const float* kv0 = (const float*)d_in[1];
  const float* k0  = (const float*)d_in[2];
  const float* bq  = (const float*)d_in[4];
  const float* bk  = (const float*)d_in[6];
  const float* bv  = (const float*)d_in[8];
  const float* bo  = (const float*)d_in[10];
  float* out = (float*)d_out;
  char* ws = (char*)d_ws;
  size_t off = 0;
  auto take = [&](size_t bytes) { char* p = ws + off; off += (bytes + 255) & ~(size_t)255; return p; };
  u16*   xb     = (u16*)  take((size_t)BATCH * SEQ * DM * 2);
  u16*   wqkvT  = (u16*)  take((size_t)1536 * DM * 2);
  u16*   woT    = (u16*)  take((size_t)DM * DM * 2);
  float* bias_a = (float*)take((size_t)1536 * 4);
  float* qkw    = (float*)take((size_t)BATCH * SEQ * QKS * 4);
  u16*   vbT    = (u16*)  take((size_t)BATCH * SEQ * DM * 2);
  u16*   ckvT   = (u16*)  take((size_t)BH * NC * EXPP * HD * 2);
  float* ck     = (float*)take((size_t)BH * NC * EXPP * 4);
  u16*   ob     = (u16*)  take((size_t)BATCH * SEQ * DM * 2);
  if (off > ws_size) return;

  float* out_kv = out + (size_t)BATCH * SEQ * DM;
  float* out_k  = out_kv + (size_t)BH * EXPD * HD;

  prep<<<8192 + 2560 + 6, 256, 0, stream>>>(x, xb,
      (const float*)d_in[3], (const float*)d_in[5], (const float*)d_in[7], (const float*)d_in[9],
      wqkvT, woT, bq, bk, bv, bias_a);

  gemmQKV<<<dim3(8, 64), 256, 0, stream>>>(xb, wqkvT, bias_a, qkw, vbT);

  chunk_sums<<<BH * NC, 256, 0, stream>>>(qkw, vbT, ckvT, ck);
  kv_prefix<<<BH * 10, 256, 0, stream>>>(ckvT, kv0, out_kv, ck, k0, out_k);
  out_chunk<<<BH * NC, 256, 0, stream>>>(qkw, vbT, ckvT, ck, ob);

  gemm128<<<dim3(8, 64), 256, 0, stream>>>(ob, woT, bo, MROWS, DM, DM, out);
}

// Round 9
// 268.459 us; speedup vs baseline: 1.0273x; 1.0022x over previous
//
#include <hip/hip_runtime.h>

typedef unsigned short u16;
typedef __attribute__((ext_vector_type(8))) short bf16x8;
typedef __attribute__((ext_vector_type(4))) float f32x4;

#define BATCH 4
#define SEQ   2048
#define DM    1024
#define HEADS 16
#define FEAT  16
#define HD    64
#define EXPD  273
#define EXPP  288   // padded to multiple of 32 for MFMA K
#define CHK   128
#define NC    16    // SEQ / CHK
#define BH    64    // BATCH*HEADS
#define QKS   512   // fused QK projection row stride
#define MROWS 8192  // BATCH*SEQ
#define C2    0.17677669529663687f  // 1/(sqrt(2)*sqrt(16))

__device__ __forceinline__ u16 f2b(float f) {
  union { float f; unsigned u; } v; v.f = f;
  unsigned u = v.u;
  return (u16)((u + 0x7fffu + ((u >> 16) & 1u)) >> 16);
}
__device__ __forceinline__ float b2f(u16 s) {
  union { unsigned u; float f; } v; v.u = ((unsigned)s) << 16; return v.f;
}
// HW packed bf16 convert (RTNE): lo=bf16(a), hi=bf16(b) in one VALU op.
__device__ __forceinline__ unsigned pk2b(float a, float b) {
  unsigned r;
  asm("v_cvt_pk_bf16_f32 %0, %1, %2" : "=v"(r) : "v"(a), "v"(b));
  return r;
}

typedef const unsigned int __attribute__((address_space(1)))* gas1;
typedef unsigned int __attribute__((address_space(3)))* las3;
__device__ __forceinline__ void gl_lds16(const u16* g, u16* l) {
  __builtin_amdgcn_global_load_lds((gas1)(const void*)g, (las3)(void*)l, 16, 0, 0);
}

// Fused prep: x->bf16 (0..8191), weight cast-transposes (8192..10751), bias concat (10752..10757)
__global__ __launch_bounds__(256) void prep(const float* __restrict__ x, u16* __restrict__ xb,
                                            const float* __restrict__ Wq, const float* __restrict__ Wk,
                                            const float* __restrict__ Wv, const float* __restrict__ Wo,
                                            u16* __restrict__ wqkvT, u16* __restrict__ woT,
                                            const float* __restrict__ bq, const float* __restrict__ bk,
                                            const float* __restrict__ bv, float* __restrict__ bias_all) {
  __shared__ float tile[32][33];
  int id = blockIdx.x;
  if (id < 8192) {
    int i = id * 256 + threadIdx.x;
    float4 v = ((const float4*)x)[i];
    uint2 r; r.x = pk2b(v.x, v.y); r.y = pk2b(v.z, v.w);
    ((uint2*)xb)[i] = r;
    return;
  }
  id -= 8192;
  if (id < 2560) {
    const float* src; u16* dst; int N, t;
    if (id < 256)       { src = Wq; dst = wqkvT;            N = 256;  t = id; }
    else if (id < 512)  { src = Wk; dst = wqkvT + 256 * DM; N = 256;  t = id - 256; }
    else if (id < 1536) { src = Wv; dst = wqkvT + 512 * DM; N = 1024; t = id - 512; }
    else                { src = Wo; dst = woT;              N = 1024; t = id - 1536; }
    int nt = N / 32;
    int n0 = (t % nt) * 32, k0 = (t / nt) * 32;
    int tx = threadIdx.x & 31, ty = threadIdx.x >> 5;
    for (int i = ty; i < 32; i += 8)
      tile[i][tx] = src[(size_t)(k0 + i) * N + n0 + tx];
    __syncthreads();
    for (int i = ty; i < 32; i += 8)
      dst[(size_t)(n0 + i) * DM + k0 + tx] = f2b(tile[tx][i]);
    return;
  }
  id -= 2560;
  int i = id * 256 + threadIdx.x;  // 0..1535
  float v;
  if (i < 256) v = bq[i];
  else if (i < 512) v = bk[i - 256];
  else v = bv[i - 512];
  bias_all[i] = v;
}

// Fused QKV projection: C = xb @ wqkvT^T + bias_all. N=1536.
// R9: TRIPLE-buffered LDS, distance-2 prefetch (AITER pattern): tile t staged
// 2 K-steps before compute; steady-state vmcnt(10) = 2 stages in flight, never
// drains. Tile 128x192, grid 8x64 = 512 blocks = 2/CU. LDS 61,440 B.
__global__ __launch_bounds__(256, 2) void gemmQKV(const u16* __restrict__ A, const u16* __restrict__ BT,
                                                  const float* __restrict__ bias,
                                                  float* __restrict__ qkw, u16* __restrict__ vbT) {
  __shared__ __align__(16) u16 As[3][128 * 32];
  __shared__ __align__(16) u16 Bs[3][192 * 32];
  const int tid = threadIdx.x;
  const int wave = tid >> 6, lane = tid & 63, qd = lane >> 4, ln = lane & 15;
  const int wr = (wave >> 1) * 64, wc = (wave & 1) * 96;
  const int m0 = blockIdx.y * 128, n0 = blockIdx.x * 192;
  const int K = DM;
  f32x4 acc[4][6];
#pragma unroll
  for (int i = 0; i < 4; i++)
#pragma unroll
    for (int j = 0; j < 6; j++) acc[i][j] = (f32x4){0.f, 0.f, 0.f, 0.f};
  const int sr = tid >> 2;
  const int scs = (((tid & 3) ^ ((sr >> 1) & 3))) * 8;   // u16 offset of swizzled source chunk
  const u16* gA0 = A + (size_t)(m0 + sr) * K + scs;
  const u16* gA1 = gA0 + (size_t)64 * K;
  const u16* gB0 = BT + (size_t)(n0 + sr) * K + scs;
  auto stage = [&](int buf, int kk) {
    gl_lds16(gA0 + kk, &As[buf][wave * 512]);
    gl_lds16(gA1 + kk, &As[buf][2048 + wave * 512]);
    gl_lds16(gB0 + kk,                   &Bs[buf][wave * 512]);
    gl_lds16(gB0 + (size_t)64 * K + kk,  &Bs[buf][2048 + wave * 512]);
    gl_lds16(gB0 + (size_t)128 * K + kk, &Bs[buf][4096 + wave * 512]);
  };
  const int swz = ((ln >> 1) & 3) << 3;
  auto compute = [&](int buf) {
    bf16x8 af[4], bf[6];
#pragma unroll
    for (int t = 0; t < 4; t++)
      af[t] = *(const bf16x8*)&As[buf][(wr + t * 16 + ln) * 32 + ((qd * 8) ^ swz)];
#pragma unroll
    for (int u = 0; u < 6; u++)
      bf[u] = *(const bf16x8*)&Bs[buf][(wc + u * 16 + ln) * 32 + ((qd * 8) ^ swz)];
#pragma unroll
    for (int mt = 0; mt < 4; mt++)
#pragma unroll
      for (int nt = 0; nt < 6; nt++)
        acc[mt][nt] = __builtin_amdgcn_mfma_f32_16x16x32_bf16(af[mt], bf[nt], acc[mt][nt], 0, 0, 0);
  };
  stage(0, 0);     // tile 0 -> buf 0
  stage(1, 32);    // tile 1 -> buf 1
  int bufc = 0;
  for (int kk = 64; kk < K; kk += 32) {   // stages tile kk/32 into buf (bufc+2)%3
    stage((bufc + 2) % 3, kk);
    asm volatile("s_waitcnt vmcnt(10)" ::: "memory");  // tile bufc's loads retired
    __builtin_amdgcn_s_barrier();
    asm volatile("" ::: "memory");
    compute(bufc);
    asm volatile("" ::: "memory");
    __builtin_amdgcn_s_barrier();          // all reads of bufc done before its restage
    bufc = (bufc + 1) % 3;
  }
  // tail: tiles 30 (buf bufc) and 31 (buf bufc+1) staged, not yet computed
  asm volatile("s_waitcnt vmcnt(5)" ::: "memory");
  __builtin_amdgcn_s_barrier();
  asm volatile("" ::: "memory");
  compute(bufc);
  asm volatile("s_waitcnt vmcnt(0)" ::: "memory");
  __builtin_amdgcn_s_barrier();
  asm volatile("" ::: "memory");
  compute((bufc + 1) % 3);
#pragma unroll
  for (int nt = 0; nt < 6; nt++) {
    int col = n0 + wc + nt * 16 + ln;
    float bv = bias[col];
    if (col < 512) {
#pragma unroll
      for (int mt = 0; mt < 4; mt++)
#pragma unroll
        for (int r = 0; r < 4; r++) {
          int row = m0 + wr + mt * 16 + qd * 4 + r;
          qkw[(size_t)row * QKS + col] = acc[mt][nt][r] + bv;
        }
    } else {
      int vcol = col - 512;
#pragma unroll
      for (int mt = 0; mt < 4; mt++) {
        uint2 pp;
        pp.x = pk2b(acc[mt][nt][0] + bv, acc[mt][nt][1] + bv);
        pp.y = pk2b(acc[mt][nt][2] + bv, acc[mt][nt][3] + bv);
        int row0 = m0 + wr + mt * 16 + qd * 4;
        *(uint2*)&vbT[(size_t)vcol * MROWS + row0] = pp;
      }
    }
  }
}

// C = A(MxK bf16 rm) @ BT^T + bias -> fp32 rm (O projection).
// R9: triple-buffered, distance-2 prefetch, vmcnt(8) steady state. LDS 49,152 B.
__global__ __launch_bounds__(256, 3) void gemm128(const u16* __restrict__ A, const u16* __restrict__ BT,
                                                  const float* __restrict__ bias, int M, int N, int K,
                                                  float* __restrict__ outF) {
  __shared__ __align__(16) u16 As[3][128 * 32];
  __shared__ __align__(16) u16 Bs[3][128 * 32];
  const int tid = threadIdx.x;
  const int wave = tid >> 6, lane = tid & 63, qd = lane >> 4, ln = lane & 15;
  const int wr = (wave >> 1) * 64, wc = (wave & 1) * 64;
  const int m0 = blockIdx.y * 128, n0 = blockIdx.x * 128;
  f32x4 acc[4][4];
#pragma unroll
  for (int i = 0; i < 4; i++)
#pragma unroll
    for (int j = 0; j < 4; j++) acc[i][j] = (f32x4){0.f, 0.f, 0.f, 0.f};
  const int sr = tid >> 2;
  const int scs = (((tid & 3) ^ ((sr >> 1) & 3))) * 8;
  const u16* gA0 = A + (size_t)(m0 + sr) * K + scs;
  const u16* gA1 = gA0 + (size_t)64 * K;
  const u16* gB0 = BT + (size_t)(n0 + sr) * K + scs;
  const u16* gB1 = gB0 + (size_t)64 * K;
  auto stage = [&](int buf, int kk) {
    gl_lds16(gA0 + kk, &As[buf][wave * 512]);
    gl_lds16(gA1 + kk, &As[buf][2048 + wave * 512]);
    gl_lds16(gB0 + kk, &Bs[buf][wave * 512]);
    gl_lds16(gB1 + kk, &Bs[buf][2048 + wave * 512]);
  };
  const int swz = ((ln >> 1) & 3) << 3;
  auto compute = [&](int buf) {
    bf16x8 af[4], bf[4];
#pragma unroll
    for (int t = 0; t < 4; t++)
      af[t] = *(const bf16x8*)&As[buf][(wr + t * 16 + ln) * 32 + ((qd * 8) ^ swz)];
#pragma unroll
    for (int u = 0; u < 4; u++)
      bf[u] = *(const bf16x8*)&Bs[buf][(wc + u * 16 + ln) * 32 + ((qd * 8) ^ swz)];
#pragma unroll
    for (int mt = 0; mt < 4; mt++)
#pragma unroll
      for (int nt = 0; nt < 4; nt++)
        acc[mt][nt] = __builtin_amdgcn_mfma_f32_16x16x32_bf16(af[mt], bf[nt], acc[mt][nt], 0, 0, 0);
  };
  stage(0, 0);
  stage(1, 32);
  int bufc = 0;
  for (int kk = 64; kk < K; kk += 32) {
    stage((bufc + 2) % 3, kk);
    asm volatile("s_waitcnt vmcnt(8)" ::: "memory");
    __builtin_amdgcn_s_barrier();
    asm volatile("" ::: "memory");
    compute(bufc);
    asm volatile("" ::: "memory");
    __builtin_amdgcn_s_barrier();
    bufc = (bufc + 1) % 3;
  }
  asm volatile("s_waitcnt vmcnt(4)" ::: "memory");
  __builtin_amdgcn_s_barrier();
  asm volatile("" ::: "memory");
  compute(bufc);
  asm volatile("s_waitcnt vmcnt(0)" ::: "memory");
  __builtin_amdgcn_s_barrier();
  asm volatile("" ::: "memory");
  compute((bufc + 1) % 3);
#pragma unroll
  for (int nt = 0; nt < 4; nt++) {
    int col = n0 + wc + nt * 16 + ln;
    float bv = bias[col];
#pragma unroll
    for (int mt = 0; mt < 4; mt++)
#pragma unroll
      for (int r = 0; r < 4; r++) {
        int row = m0 + wr + mt * 16 + qd * 4 + r;
        outF[(size_t)row * N + col] = acc[mt][nt][r] + bv;
      }
  }
}

// Register-q featurize of a 32-el chunk (e = 32*KT + 16*p .. +15) into dst (contiguous 16 u16).
template<int KT>
__device__ __forceinline__ void feat_row(const float* q16, int p, u16* dst) {
  float v[16];
  if (KT == 0 && p == 0) {
    v[0] = 1.0f;
#pragma unroll
    for (int j = 1; j < 16; j++) v[j] = 0.5f * q16[j - 1];
  } else if (KT == 0) {  // p==1: e=16..31
    v[0] = 0.5f * q16[15];
    float wm = C2 * q16[0];
#pragma unroll
    for (int j = 1; j < 16; j++) v[j] = wm * q16[j - 1];
  } else {
    constexpr int c = 2 * KT;
    float wm = C2 * (p ? q16[c]     : q16[c - 1]);
    float w0 = C2 * (p ? q16[c - 1] : q16[c - 2]);
    v[0] = w0 * q16[15];
#pragma unroll
    for (int j = 1; j < 16; j++) v[j] = wm * q16[j - 1];
    if (KT == 8 && p) {  // e >= 273 -> 0
#pragma unroll
      for (int j = 1; j < 16; j++) v[j] = 0.f;
    }
  }
  unsigned w[8];
#pragma unroll
  for (int j = 0; j < 8; j++) w[j] = pk2b(v[2 * j], v[2 * j + 1]);
  *(uint4*)dst = *(uint4*)w;
  *(uint4*)(dst + 8) = *(uint4*)(w + 4);
}

// Register-k featurize for chunk_sums: mt = MTB + 2p -> buffer (mt & 3), [el][t] layout
template<int MTB>
__device__ __forceinline__ void kfeat(const float* k16, int p, int t2, u16 (*kfT)[16][136]) {
  float v[16];
  if (MTB == 0) {
    if (p == 0) {
      v[0] = 1.0f;
#pragma unroll
      for (int j = 1; j < 16; j++) v[j] = 0.5f * k16[j - 1];
    } else {
      float w0 = C2 * k16[0], wm = C2 * k16[1];
      v[0] = w0 * k16[15];
#pragma unroll
      for (int j = 1; j < 16; j++) v[j] = wm * k16[j - 1];
    }
  } else if (MTB == 1) {
    if (p == 0) {
      v[0] = 0.5f * k16[15];
      float wm = C2 * k16[0];
#pragma unroll
      for (int j = 1; j < 16; j++) v[j] = wm * k16[j - 1];
    } else {
      float w0 = C2 * k16[1], wm = C2 * k16[2];
      v[0] = w0 * k16[15];
#pragma unroll
      for (int j = 1; j < 16; j++) v[j] = wm * k16[j - 1];
    }
  } else {
    float wm = C2 * (p ? k16[MTB + 1] : k16[MTB - 1]);
    float w0 = C2 * (p ? k16[MTB]     : k16[MTB - 2]);
    v[0] = w0 * k16[15];
#pragma unroll
    for (int j = 1; j < 16; j++) v[j] = wm * k16[j - 1];
  }
  union { unsigned w[8]; u16 s[16]; } u;
#pragma unroll
  for (int j = 0; j < 8; j++) u.w[j] = pk2b(v[2 * j], v[2 * j + 1]);
  int b = 2 * p + (MTB & 1);
#pragma unroll
  for (int el = 0; el < 16; el++) kfT[b][el][t2] = u.s[el];
}

// Per (b,h,chunk of 128): ckvT[hd][e] = sum_t Kf[t][e]*V[t][hd] (bf16), ck[e] = colsum Kf (fp32)
__global__ __launch_bounds__(256) void chunk_sums(const float* __restrict__ qkw, const u16* __restrict__ vbT,
                                                  u16* __restrict__ ckvT, float* __restrict__ ck) {
  __shared__ float kl[CHK][20];
  __shared__ __align__(16) u16 kfT[4][16][136];
  const int tid = threadIdx.x;
  const int bh = blockIdx.x / NC, c = blockIdx.x % NC;
  const int b = bh >> 4, h = bh & 15;
  const int wave = tid >> 6, lane = tid & 63, qd = lane >> 4, ln = lane & 15;
  const int t2 = tid >> 1, p = tid & 1;
  const size_t rowbase = (size_t)(b * SEQ + c * CHK);
  float k16[16];
  {
    const float* kp = &qkw[(rowbase + t2) * QKS + 256 + h * FEAT];
    float4 v0 = *(const float4*)kp, v1 = *(const float4*)(kp + 4);
    float4 v2 = *(const float4*)(kp + 8), v3 = *(const float4*)(kp + 12);
    k16[0] = v0.x; k16[1] = v0.y; k16[2] = v0.z; k16[3] = v0.w;
    k16[4] = v1.x; k16[5] = v1.y; k16[6] = v1.z; k16[7] = v1.w;
    k16[8] = v2.x; k16[9] = v2.y; k16[10] = v2.z; k16[11] = v2.w;
    k16[12] = v3.x; k16[13] = v3.y; k16[14] = v3.z; k16[15] = v3.w;
    float4 h0, h1;
    if (p == 0) { h0 = v0; h1 = v1; } else { h0 = v2; h1 = v3; }
    *(float4*)&kl[t2][p * 8] = h0;
    *(float4*)&kl[t2][p * 8 + 4] = h1;
  }
  uint4 bVv[4][4];
#pragma unroll
  for (int kk2 = 0; kk2 < 4; kk2++)
#pragma unroll
    for (int nt = 0; nt < 4; nt++)
      bVv[kk2][nt] = *(const uint4*)&vbT[(size_t)(h * HD + nt * 16 + ln) * MROWS +
                                         rowbase + kk2 * 32 + qd * 8];
  const size_t obase = (size_t)(bh * NC + c) * HD;
  auto mstore = [&](int mt, int bufw) {
    f32x4 acc[4];
#pragma unroll
    for (int nt = 0; nt < 4; nt++) acc[nt] = (f32x4){0.f, 0.f, 0.f, 0.f};
#pragma unroll
    for (int kk2 = 0; kk2 < 4; kk2++) {
      bf16x8 a = *(const bf16x8*)&kfT[bufw][ln][kk2 * 32 + qd * 8];
#pragma unroll
      for (int nt = 0; nt < 4; nt++) {
        bf16x8 bb = *(const bf16x8*)&bVv[kk2][nt];
        acc[nt] = __builtin_amdgcn_mfma_f32_16x16x32_bf16(a, bb, acc[nt], 0, 0, 0);
      }
    }
#pragma unroll
    for (int nt = 0; nt < 4; nt++) {
      uint2 pp;
      pp.x = pk2b(acc[nt][0], acc[nt][1]);
      pp.y = pk2b(acc[nt][2], acc[nt][3]);
      *(uint2*)&ckvT[(obase + nt * 16 + ln) * EXPP + mt * 16 + qd * 4] = pp;
    }
  };
  __syncthreads();
  kfeat<0>(k16, p, t2, kfT); kfeat<1>(k16, p, t2, kfT);
  __syncthreads();
  mstore(wave, wave);
  __syncthreads();
  kfeat<4>(k16, p, t2, kfT); kfeat<5>(k16, p, t2, kfT);
  __syncthreads();
  mstore(4 + wave, wave);
  __syncthreads();
  kfeat<8>(k16, p, t2, kfT); kfeat<9>(k16, p, t2, kfT);
  __syncthreads();
  mstore(8 + wave, wave);
  __syncthreads();
  kfeat<12>(k16, p, t2, kfT); kfeat<13>(k16, p, t2, kfT);
  __syncthreads();
  mstore(12 + wave, wave);
  __syncthreads();
  {  // mts 16,17 -> buffers 0,1
    float v[16];
    if (p == 0) {
      float w0 = C2 * k16[14], wm = C2 * k16[15];
      v[0] = w0 * k16[15];
#pragma unroll
      for (int j = 1; j < 16; j++) v[j] = wm * k16[j - 1];
    } else {
      v[0] = C2 * k16[15] * k16[15];
#pragma unroll
      for (int j = 1; j < 16; j++) v[j] = 0.f;
    }
    union { unsigned w[8]; u16 s[16]; } u;
#pragma unroll
    for (int j = 0; j < 8; j++) u.w[j] = pk2b(v[2 * j], v[2 * j + 1]);
#pragma unroll
    for (int el = 0; el < 16; el++) kfT[p][el][t2] = u.s[el];
  }
  __syncthreads();
  if (wave < 2) mstore(16 + wave, wave);
  for (int e = tid; e < EXPP; e += 256) {
    float s = 0.f;
    if (e == 0) s = (float)CHK;
    else if (e < 17) { float t = 0.f; for (int tt = 0; tt < CHK; tt++) t += kl[tt][e - 1]; s = 0.5f * t; }
    else if (e < EXPD) {
      int u = e - 17, i0 = u >> 4, j0 = u & 15; float t = 0.f;
      for (int tt = 0; tt < CHK; tt++) t += kl[tt][i0] * kl[tt][j0];
      s = C2 * t;
    }
    ck[(size_t)(bh * NC + c) * EXPP + e] = s;
  }
}

// Exclusive prefix over chunks (in place, bf16) on ckvT; inclusive final -> out_kv.
__global__ __launch_bounds__(256) void kv_prefix(u16* __restrict__ ckvT, const float* __restrict__ kv0,
                                                 float* __restrict__ out_kv,
                                                 float* __restrict__ ck, const float* __restrict__ k0,
                                                 float* __restrict__ out_k) {
  const int tid = threadIdx.x;
  const int bh = blockIdx.x / 10, eg = blockIdx.x % 10;
  if (eg == 9) {
    for (int e = tid; e < EXPP; e += 256) {
      float S = (e < EXPD) ? k0[(size_t)bh * EXPD + e] : 0.f;
      for (int c = 0; c < NC; c++) {
        size_t idx = ((size_t)bh * NC + c) * EXPP + e;
        float v = ck[idx];
        ck[idx] = S;
        S += v;
      }
      if (e < EXPD) out_k[(size_t)bh * EXPD + e] = S;
    }
    return;
  }
  const int hd = tid >> 2;
  const int e0 = eg * 32 + (tid & 3) * 8;
  float S[8];
#pragma unroll
  for (int j = 0; j < 8; j++) {
    int e = e0 + j;
    S[j] = (e < EXPD) ? kv0[((size_t)bh * EXPD + e) * HD + hd] : 0.f;
  }
  u16* base = ckvT + ((size_t)bh * NC * HD + hd) * EXPP + e0;
  const size_t cstride = (size_t)HD * EXPP;
  uint4 v0 = *(const uint4*)base;
  uint4 v1 = *(const uint4*)(base + cstride);
  for (int c = 0; c < NC; c++) {
    uint4 vn = v1;
    if (c + 2 < NC) vn = *(const uint4*)(base + (size_t)(c + 2) * cstride);
    union { uint4 q; unsigned w[4]; } pk;
#pragma unroll
    for (int j = 0; j < 4; j++) pk.w[j] = pk2b(S[2 * j], S[2 * j + 1]);
    *(uint4*)(base + (size_t)c * cstride) = pk.q;
    union { uint4 q; u16 s[8]; } vv; vv.q = v0;
#pragma unroll
    for (int j = 0; j < 8; j++) S[j] += b2f(vv.s[j]);
    v0 = v1; v1 = vn;
  }
#pragma unroll
  for (int j = 0; j < 8; j++) {
    int e = e0 + j;
    if (e < EXPD) out_kv[((size_t)bh * EXPD + e) * HD + hd] = S[j];
  }
}

// Per (b,h,chunk of 128): O = (Qf@S + mask_incl(poly(QK^T))@V) / den.
// R8 structure (kept): quad-buffered Qf -> 2 chunks per barrier, zero-slab,
// setprio around MFMA clusters. 51,200B pool, 3 blocks/CU.
__global__ __launch_bounds__(256) void out_chunk(const float* __restrict__ qkw, const u16* __restrict__ vbT,
                                                 const u16* __restrict__ ckvT, const float* __restrict__ ck,
                                                 u16* __restrict__ ob) {
  __shared__ __align__(16) u16 pool[25600];   // 51,200 B
  __shared__ float kstl[EXPP];
  __shared__ float denl[CHK];
  u16 (*qlb)[16] = (u16(*)[16])pool;                  // 128x16 (no zero half)
  u16 (*klb)[16] = (u16(*)[16])(pool + 2048);         // 128x16 (no zero half)
  u16* zslab     = pool + 4096;                       // 8 u16 shared zeros (16B)
  u16 (*qf0)[40] = (u16(*)[40])(pool + 4104);         // Qf quad buffers
  u16 (*qf1)[40] = (u16(*)[40])(pool + 9224);
  u16 (*qf2)[40] = (u16(*)[40])(pool + 14344);
  u16 (*qf3)[40] = (u16(*)[40])(pool + 19464);        // ends 24,584
  u16 (*alB)[72] = (u16(*)[72])pool;                  // scores s=64..127 (overlays qlb/klb/zslab/qf0-head)
  u16 (*alA)[72] = (u16(*)[72])(pool + 9216);         // scores s=0..63   (overlays qf1/qf2-head)
  const int tid = threadIdx.x;
  const int bh = blockIdx.x / NC, c = blockIdx.x % NC;
  const int b = bh >> 4, h = bh & 15;
  const int wave = tid >> 6, lane = tid & 63, qd = lane >> 4, ln = lane & 15;
  const int t2 = tid >> 1, p = tid & 1;
  const size_t rowbase = (size_t)(b * SEQ + c * CHK);
  float q16[16];
  {
    const float* qp = &qkw[(rowbase + t2) * QKS + h * FEAT];
    float4 v0 = *(const float4*)qp, v1 = *(const float4*)(qp + 4);
    float4 v2 = *(const float4*)(qp + 8), v3 = *(const float4*)(qp + 12);
    q16[0] = v0.x; q16[1] = v0.y; q16[2] = v0.z; q16[3] = v0.w;
    q16[4] = v1.x; q16[5] = v1.y; q16[6] = v1.z; q16[7] = v1.w;
    q16[8] = v2.x; q16[9] = v2.y; q16[10] = v2.z; q16[11] = v2.w;
    q16[12] = v3.x; q16[13] = v3.y; q16[14] = v3.z; q16[15] = v3.w;
    unsigned qw[4];
#pragma unroll
    for (int j = 0; j < 4; j++) qw[j] = pk2b(q16[p * 8 + 2 * j], q16[p * 8 + 2 * j + 1]);
    *(uint4*)&qlb[t2][p * 8] = *(uint4*)qw;
    const float* kp = &qkw[(rowbase + t2) * QKS + 256 + h * FEAT + p * 8];
    float4 k0v = *(const float4*)kp, k1v = *(const float4*)(kp + 4);
    unsigned kw[4] = {pk2b(k0v.x, k0v.y), pk2b(k0v.z, k0v.w),
                      pk2b(k1v.x, k1v.y), pk2b(k1v.z, k1v.w)};
    *(uint4*)&klb[t2][p * 8] = *(uint4*)kw;
    if (tid == 0) *(uint4*)zslab = (uint4){0u, 0u, 0u, 0u};
  }
  const size_t cbase = (size_t)(bh * NC + c);
  for (int e = tid; e < EXPP; e += 256) kstl[e] = ck[cbase * EXPP + e];
  const u16* sptr = ckvT + (cbase * HD + wave * 16 + ln) * EXPP + qd * 8;
  // 4-slot rolling S-fragment buffer: slot = kt & 3; pairs prefetched 1 phase ahead
  uint4 bSv[4];
  bSv[0] = *(const uint4*)(sptr + 0 * 32);
  bSv[1] = *(const uint4*)(sptr + 1 * 32);
  feat_row<0>(q16, p, &qf0[t2][p * 16]);
  feat_row<1>(q16, p, &qf1[t2][p * 16]);
  f32x4 accO[8];
#pragma unroll
  for (int nt = 0; nt < 8; nt++) accO[nt] = (f32x4){0.f, 0.f, 0.f, 0.f};
  // per chunk: 4+4 bQ sub-batched MFMA (R7 style), setprio around MFMA
#define CHUNK(KT, QF)                                                                      \
  {                                                                                        \
    bf16x8 aS = *(const bf16x8*)&bSv[(KT) & 3];                                            \
    bf16x8 bq0[4];                                                                         \
    _Pragma("unroll")                                                                      \
    for (int nt = 0; nt < 4; nt++) bq0[nt] = *(const bf16x8*)&QF[nt * 16 + ln][qd * 8];    \
    __builtin_amdgcn_s_setprio(1);                                                         \
    _Pragma("unroll")                                                                      \
    for (int nt = 0; nt < 4; nt++)                                                         \
      accO[nt] = __builtin_amdgcn_mfma_f32_16x16x32_bf16(aS, bq0[nt], accO[nt], 0, 0, 0);  \
    _Pragma("unroll")                                                                      \
    for (int nt = 4; nt < 8; nt++) {                                                       \
      bf16x8 bq1 = *(const bf16x8*)&QF[nt * 16 + ln][qd * 8];                              \
      accO[nt] = __builtin_amdgcn_mfma_f32_16x16x32_bf16(aS, bq1, accO[nt], 0, 0, 0);      \
    }                                                                                      \
    __builtin_amdgcn_s_setprio(0);                                                         \
  }
  // PH0: chunks 0,1 (qf0,qf1); prefetch S2,S3; feat 2,3 -> qf2,qf3
  __syncthreads();
  bSv[2] = *(const uint4*)(sptr + 2 * 32);
  bSv[3] = *(const uint4*)(sptr + 3 * 32);
  CHUNK(0, qf0)
  feat_row<2>(q16, p, &qf2[t2][p * 16]);
  CHUNK(1, qf1)
  feat_row<3>(q16, p, &qf3[t2][p * 16]);
  // PH1: chunks 2,3 (qf2,qf3); prefetch S4,S5; feat 4,5 -> qf0,qf1
  __syncthreads();
  bSv[0] = *(const uint4*)(sptr + 4 * 32);
  bSv[1] = *(const uint4*)(sptr + 5 * 32);
  CHUNK(2, qf2)
  feat_row<4>(q16, p, &qf0[t2][p * 16]);
  CHUNK(3, qf3)
  feat_row<5>(q16, p, &qf1[t2][p * 16]);
  // PH2: chunks 4,5 (qf0,qf1); prefetch S6,S7; feat 6,7 -> qf2,qf3
  __syncthreads();
  bSv[2] = *(const uint4*)(sptr + 6 * 32);
  bSv[3] = *(const uint4*)(sptr + 7 * 32);
  CHUNK(4, qf0)
  feat_row<6>(q16, p, &qf2[t2][p * 16]);
  CHUNK(5, qf1)
  feat_row<7>(q16, p, &qf3[t2][p * 16]);
  // PH3: chunks 6,7 (qf2,qf3); prefetch S8 -> slot 0; feat 8 -> qf0
  __syncthreads();
  bSv[0] = *(const uint4*)(sptr + 8 * 32);
  CHUNK(6, qf2)
  feat_row<8>(q16, p, &qf0[t2][p * 16]);
  CHUNK(7, qf3)
  // FIN: chunk 8 (qf0), aS = bSv[8&3=0]
  __syncthreads();
  CHUNK(8, qf0)
#undef CHUNK
  __syncthreads();   // all waves done reading qf buffers -> alA region free
  // hoisted denominator polynomial (q16 dies here; before scores)
  float s_poly;
  {
    float s = 0.f;
#pragma unroll
    for (int i2 = 0; i2 < 8; i2++) {
      int i = p * 8 + i2;
      float inner = 0.f;
#pragma unroll
      for (int j = 0; j < 16; j++) inner += q16[j] * kstl[17 + i * 16 + j];
      s += q16[i] * inner;
    }
    s *= C2;
    float s1 = 0.f;
#pragma unroll
    for (int j2 = 0; j2 < 8; j2++) s1 += q16[p * 8 + j2] * kstl[1 + p * 8 + j2];
    s += 0.5f * s1;
    if (p == 0) s += kstl[0] + 1e-6f;
    s_poly = s;
  }
  // scores st2=0: s-tile = wave (s 0..63) -> alA. K=32 MFMA with zero-slab for
  // the k>=16 half: lanes qd>=2 read the shared 16B zero row (broadcast, free).
  {
    const u16* kap = (qd < 2) ? &klb[wave * 16 + ln][qd * 8] : zslab;
    bf16x8 aK = *(const bf16x8*)kap;
#pragma unroll
    for (int nn = 0; nn < 2; nn++) {
      f32x4 accU[4];
      __builtin_amdgcn_s_setprio(1);
#pragma unroll
      for (int j = 0; j < 4; j++) {
        const u16* qap = (qd < 2) ? &qlb[(nn * 4 + j) * 16 + ln][qd * 8] : zslab;
        bf16x8 bQ = *(const bf16x8*)qap;
        accU[j] = __builtin_amdgcn_mfma_f32_16x16x32_bf16(aK, bQ, (f32x4){0.f, 0.f, 0.f, 0.f}, 0, 0, 0);
      }
      __builtin_amdgcn_s_setprio(0);
#pragma unroll
      for (int j = 0; j < 4; j++) {
        int t = (nn * 4 + j) * 16 + ln, sb = wave * 16 + qd * 4;
        float scm[4];
#pragma unroll
        for (int r = 0; r < 4; r++) {
          float u = accU[j][r];
          float sc = 1.f + 0.25f * u + 0.03125f * u * u;
          scm[r] = (sb + r <= t) ? sc : 0.f;
        }
        uint2 pp; pp.x = pk2b(scm[0], scm[1]); pp.y = pk2b(scm[2], scm[3]);
        *(uint2*)&alA[t][sb] = pp;
      }
    }
  }
  // scores st2=1: s-tile = wave+4 (s 64..127) -> alB (overlays qlb/klb; must
  // finish ALL reads before any write -> accU[8] held across the barrier).
  {
    f32x4 accU[8];
    const u16* kap = (qd < 2) ? &klb[(wave + 4) * 16 + ln][qd * 8] : zslab;
    bf16x8 aK = *(const bf16x8*)kap;
    __builtin_amdgcn_s_setprio(1);
#pragma unroll
    for (int nt = 0; nt < 8; nt++) {
      const u16* qap = (qd < 2) ? &qlb[nt * 16 + ln][qd * 8] : zslab;
      bf16x8 bQ = *(const bf16x8*)qap;
      accU[nt] = __builtin_amdgcn_mfma_f32_16x16x32_bf16(aK, bQ, (f32x4){0.f, 0.f, 0.f, 0.f}, 0, 0, 0);
    }
    __builtin_amdgcn_s_setprio(0);
    // V fragments issued here: latency hides under alB pack/write + barrier
    uint4 bVv[4];
#pragma unroll
    for (int kk2 = 0; kk2 < 4; kk2++)
      bVv[kk2] = *(const uint4*)&vbT[(size_t)(h * HD + wave * 16 + ln) * MROWS +
                                     rowbase + kk2 * 32 + qd * 8];
    __syncthreads();   // all qlb/klb/zslab reads complete before alB overwrite
#pragma unroll
    for (int nt = 0; nt < 8; nt++) {
      int t = nt * 16 + ln, sbl = wave * 16 + qd * 4;
      float scm[4];
#pragma unroll
      for (int r = 0; r < 4; r++) {
        float u = accU[nt][r];
        float sc = 1.f + 0.25f * u + 0.03125f * u * u;
        scm[r] = (64 + sbl + r <= t) ? sc : 0.f;
      }
      uint2 pp; pp.x = pk2b(scm[0], scm[1]); pp.y = pk2b(scm[2], scm[3]);
      *(uint2*)&alB[t][sbl] = pp;
    }
    __syncthreads();
    // A@V: A = V frags (registers), B = al rows
    __builtin_amdgcn_s_setprio(1);
#pragma unroll
    for (int kk2 = 0; kk2 < 4; kk2++) {
      bf16x8 aV = *(const bf16x8*)&bVv[kk2];
#pragma unroll
      for (int nt = 0; nt < 8; nt++) {
        bf16x8 bA = (kk2 < 2) ? *(const bf16x8*)&alA[nt * 16 + ln][kk2 * 32 + qd * 8]
                              : *(const bf16x8*)&alB[nt * 16 + ln][(kk2 - 2) * 32 + qd * 8];
        accO[nt] = __builtin_amdgcn_mfma_f32_16x16x32_bf16(aV, bA, accO[nt], 0, 0, 0);
      }
    }
    __builtin_amdgcn_s_setprio(0);
  }
  // denominator: row-sum of al + hoisted polynomial
  {
    const u16* arow = p ? &alB[t2][0] : &alA[t2][0];
    float da = 0.f;
#pragma unroll
    for (int sb = 0; sb < 8; sb++) {
      union { uint4 q; u16 hh[8]; } uu;
      uu.q = *(const uint4*)(arow + sb * 8);
#pragma unroll
      for (int j = 0; j < 8; j++) da += b2f(uu.hh[j]);
    }
    float s = s_poly + da;
    s += __shfl_xor(s, 1);
    if (p == 0) denl[t2] = s;
  }
  __syncthreads();
  // output: lane holds hd = wave*16+qd*4+r, t = nt*16+ln -> packed uint2 along hd
#pragma unroll
  for (int nt = 0; nt < 8; nt++) {
    int t = nt * 16 + ln;
    float rd = 1.0f / denl[t];
    uint2 pp;
    pp.x = pk2b(accO[nt][0] * rd, accO[nt][1] * rd);
    pp.y = pk2b(accO[nt][2] * rd, accO[nt][3] * rd);
    *(uint2*)&ob[(rowbase + t) * DM + h * HD + wave * 16 + qd * 4] = pp;
  }
}

extern "C" void kernel_launch(void* const* d_in, const int* in_sizes, int n_in,
                              void* d_out, int out_size, void* d_ws, size_t ws_size,
                              hipStream_t stream) {
  (void)in_sizes; (void)n_in; (void)out_size;
  const float* x   = (const float*)d_in[0];
  const float* kv0 = (const float*)d_in[1];
  const float* k0  = (const float*)d_in[2];
  const float* bq  = (const float*)d_in[4];
  const float* bk  = (const float*)d_in[6];
  const float* bv  = (const float*)d_in[8];
  const float* bo  = (const float*)d_in[10];
  float* out = (float*)d_out;
  char* ws = (char*)d_ws;
  size_t off = 0;
  auto take = [&](size_t bytes) { char* p = ws + off; off += (bytes + 255) & ~(size_t)255; return p; };
  u16*   xb     = (u16*)  take((size_t)BATCH * SEQ * DM * 2);
  u16*   wqkvT  = (u16*)  take((size_t)1536 * DM * 2);
  u16*   woT    = (u16*)  take((size_t)DM * DM * 2);
  float* bias_a = (float*)take((size_t)1536 * 4);
  float* qkw    = (float*)take((size_t)BATCH * SEQ * QKS * 4);
  u16*   vbT    = (u16*)  take((size_t)BATCH * SEQ * DM * 2);
  u16*   ckvT   = (u16*)  take((size_t)BH * NC * EXPP * HD * 2);
  float* ck     = (float*)take((size_t)BH * NC * EXPP * 4);
  u16*   ob     = (u16*)  take((size_t)BATCH * SEQ * DM * 2);
  if (off > ws_size) return;

  float* out_kv = out + (size_t)BATCH * SEQ * DM;
  float* out_k  = out_kv + (size_t)BH * EXPD * HD;

  prep<<<8192 + 2560 + 6, 256, 0, stream>>>(x, xb,
      (const float*)d_in[3], (const float*)d_in[5], (const float*)d_in[7], (const float*)d_in[9],
      wqkvT, woT, bq, bk, bv, bias_a);

  gemmQKV<<<dim3(8, 64), 256, 0, stream>>>(xb, wqkvT, bias_a, qkw, vbT);

  chunk_sums<<<BH * NC, 256, 0, stream>>>(qkw, vbT, ckvT, ck);
  kv_prefix<<<BH * 10, 256, 0, stream>>>(ckvT, kv0, out_kv, ck, k0, out_k);
  out_chunk<<<BH * NC, 256, 0, stream>>>(qkw, vbT, ckvT, ck, ob);

  gemm128<<<dim3(8, 64), 256, 0, stream>>>(ob, woT, bo, MROWS, DM, DM, out);
}

// Round 10
// 267.987 us; speedup vs baseline: 1.0291x; 1.0018x over previous
//
#include <hip/hip_runtime.h>

typedef unsigned short u16;
typedef __attribute__((ext_vector_type(8))) short bf16x8;
typedef __attribute__((ext_vector_type(4))) float f32x4;

#define BATCH 4
#define SEQ   2048
#define DM    1024
#define HEADS 16
#define FEAT  16
#define HD    64
#define EXPD  273
#define EXPP  288   // padded to multiple of 32 for MFMA K
#define CHK   128
#define NC    16    // SEQ / CHK
#define BH    64    // BATCH*HEADS
#define QKS   512   // fused QK projection row stride
#define MROWS 8192  // BATCH*SEQ
#define C2    0.17677669529663687f  // 1/(sqrt(2)*sqrt(16))

__device__ __forceinline__ u16 f2b(float f) {
  union { float f; unsigned u; } v; v.f = f;
  unsigned u = v.u;
  return (u16)((u + 0x7fffu + ((u >> 16) & 1u)) >> 16);
}
__device__ __forceinline__ float b2f(u16 s) {
  union { unsigned u; float f; } v; v.u = ((unsigned)s) << 16; return v.f;
}
// HW packed bf16 convert (RTNE): lo=bf16(a), hi=bf16(b) in one VALU op.
__device__ __forceinline__ unsigned pk2b(float a, float b) {
  unsigned r;
  asm("v_cvt_pk_bf16_f32 %0, %1, %2" : "=v"(r) : "v"(a), "v"(b));
  return r;
}

typedef const unsigned int __attribute__((address_space(1)))* gas1;
typedef unsigned int __attribute__((address_space(3)))* las3;
__device__ __forceinline__ void gl_lds16(const u16* g, u16* l) {
  __builtin_amdgcn_global_load_lds((gas1)(const void*)g, (las3)(void*)l, 16, 0, 0);
}

// Fused prep: x->bf16 (0..8191), weight cast-transposes (8192..10751), bias concat (10752..10757)
__global__ __launch_bounds__(256) void prep(const float* __restrict__ x, u16* __restrict__ xb,
                                            const float* __restrict__ Wq, const float* __restrict__ Wk,
                                            const float* __restrict__ Wv, const float* __restrict__ Wo,
                                            u16* __restrict__ wqkvT, u16* __restrict__ woT,
                                            const float* __restrict__ bq, const float* __restrict__ bk,
                                            const float* __restrict__ bv, float* __restrict__ bias_all) {
  __shared__ float tile[32][33];
  int id = blockIdx.x;
  if (id < 8192) {
    int i = id * 256 + threadIdx.x;
    float4 v = ((const float4*)x)[i];
    uint2 r; r.x = pk2b(v.x, v.y); r.y = pk2b(v.z, v.w);
    ((uint2*)xb)[i] = r;
    return;
  }
  id -= 8192;
  if (id < 2560) {
    const float* src; u16* dst; int N, t;
    if (id < 256)       { src = Wq; dst = wqkvT;            N = 256;  t = id; }
    else if (id < 512)  { src = Wk; dst = wqkvT + 256 * DM; N = 256;  t = id - 256; }
    else if (id < 1536) { src = Wv; dst = wqkvT + 512 * DM; N = 1024; t = id - 512; }
    else                { src = Wo; dst = woT;              N = 1024; t = id - 1536; }
    int nt = N / 32;
    int n0 = (t % nt) * 32, k0 = (t / nt) * 32;
    int tx = threadIdx.x & 31, ty = threadIdx.x >> 5;
    for (int i = ty; i < 32; i += 8)
      tile[i][tx] = src[(size_t)(k0 + i) * N + n0 + tx];
    __syncthreads();
    for (int i = ty; i < 32; i += 8)
      dst[(size_t)(n0 + i) * DM + k0 + tx] = f2b(tile[tx][i]);
    return;
  }
  id -= 2560;
  int i = id * 256 + threadIdx.x;  // 0..1535
  float v;
  if (i < 256) v = bq[i];
  else if (i < 512) v = bk[i - 256];
  else v = bv[i - 512];
  bias_all[i] = v;
}

// Fused QKV projection: C = xb @ wqkvT^T + bias_all. N=1536.
// R9: TRIPLE-buffered LDS, distance-2 prefetch (AITER pattern): tile t staged
// 2 K-steps before compute; steady-state vmcnt(10) = 2 stages in flight, never
// drains. Tile 128x192, grid 8x64 = 512 blocks = 2/CU. LDS 61,440 B.
__global__ __launch_bounds__(256, 2) void gemmQKV(const u16* __restrict__ A, const u16* __restrict__ BT,
                                                  const float* __restrict__ bias,
                                                  float* __restrict__ qkw, u16* __restrict__ vbT) {
  __shared__ __align__(16) u16 As[3][128 * 32];
  __shared__ __align__(16) u16 Bs[3][192 * 32];
  const int tid = threadIdx.x;
  const int wave = tid >> 6, lane = tid & 63, qd = lane >> 4, ln = lane & 15;
  const int wr = (wave >> 1) * 64, wc = (wave & 1) * 96;
  const int m0 = blockIdx.y * 128, n0 = blockIdx.x * 192;
  const int K = DM;
  f32x4 acc[4][6];
#pragma unroll
  for (int i = 0; i < 4; i++)
#pragma unroll
    for (int j = 0; j < 6; j++) acc[i][j] = (f32x4){0.f, 0.f, 0.f, 0.f};
  const int sr = tid >> 2;
  const int scs = (((tid & 3) ^ ((sr >> 1) & 3))) * 8;   // u16 offset of swizzled source chunk
  const u16* gA0 = A + (size_t)(m0 + sr) * K + scs;
  const u16* gA1 = gA0 + (size_t)64 * K;
  const u16* gB0 = BT + (size_t)(n0 + sr) * K + scs;
  auto stage = [&](int buf, int kk) {
    gl_lds16(gA0 + kk, &As[buf][wave * 512]);
    gl_lds16(gA1 + kk, &As[buf][2048 + wave * 512]);
    gl_lds16(gB0 + kk,                   &Bs[buf][wave * 512]);
    gl_lds16(gB0 + (size_t)64 * K + kk,  &Bs[buf][2048 + wave * 512]);
    gl_lds16(gB0 + (size_t)128 * K + kk, &Bs[buf][4096 + wave * 512]);
  };
  const int swz = ((ln >> 1) & 3) << 3;
  auto compute = [&](int buf) {
    bf16x8 af[4], bf[6];
#pragma unroll
    for (int t = 0; t < 4; t++)
      af[t] = *(const bf16x8*)&As[buf][(wr + t * 16 + ln) * 32 + ((qd * 8) ^ swz)];
#pragma unroll
    for (int u = 0; u < 6; u++)
      bf[u] = *(const bf16x8*)&Bs[buf][(wc + u * 16 + ln) * 32 + ((qd * 8) ^ swz)];
#pragma unroll
    for (int mt = 0; mt < 4; mt++)
#pragma unroll
      for (int nt = 0; nt < 6; nt++)
        acc[mt][nt] = __builtin_amdgcn_mfma_f32_16x16x32_bf16(af[mt], bf[nt], acc[mt][nt], 0, 0, 0);
  };
  stage(0, 0);     // tile 0 -> buf 0
  stage(1, 32);    // tile 1 -> buf 1
  int bufc = 0;
  for (int kk = 64; kk < K; kk += 32) {   // stages tile kk/32 into buf (bufc+2)%3
    stage((bufc + 2) % 3, kk);
    asm volatile("s_waitcnt vmcnt(10)" ::: "memory");  // tile bufc's loads retired
    __builtin_amdgcn_s_barrier();
    asm volatile("" ::: "memory");
    compute(bufc);
    asm volatile("" ::: "memory");
    __builtin_amdgcn_s_barrier();          // all reads of bufc done before its restage
    bufc = (bufc + 1) % 3;
  }
  // tail: tiles 30 (buf bufc) and 31 (buf bufc+1) staged, not yet computed
  asm volatile("s_waitcnt vmcnt(5)" ::: "memory");
  __builtin_amdgcn_s_barrier();
  asm volatile("" ::: "memory");
  compute(bufc);
  asm volatile("s_waitcnt vmcnt(0)" ::: "memory");
  __builtin_amdgcn_s_barrier();
  asm volatile("" ::: "memory");
  compute((bufc + 1) % 3);
#pragma unroll
  for (int nt = 0; nt < 6; nt++) {
    int col = n0 + wc + nt * 16 + ln;
    float bv = bias[col];
    if (col < 512) {
#pragma unroll
      for (int mt = 0; mt < 4; mt++)
#pragma unroll
        for (int r = 0; r < 4; r++) {
          int row = m0 + wr + mt * 16 + qd * 4 + r;
          qkw[(size_t)row * QKS + col] = acc[mt][nt][r] + bv;
        }
    } else {
      int vcol = col - 512;
#pragma unroll
      for (int mt = 0; mt < 4; mt++) {
        uint2 pp;
        pp.x = pk2b(acc[mt][nt][0] + bv, acc[mt][nt][1] + bv);
        pp.y = pk2b(acc[mt][nt][2] + bv, acc[mt][nt][3] + bv);
        int row0 = m0 + wr + mt * 16 + qd * 4;
        *(uint2*)&vbT[(size_t)vcol * MROWS + row0] = pp;
      }
    }
  }
}

// C = A(MxK bf16 rm) @ BT^T + bias -> fp32 rm (O projection).
// R9: triple-buffered, distance-2 prefetch, vmcnt(8) steady state. LDS 49,152 B.
__global__ __launch_bounds__(256, 3) void gemm128(const u16* __restrict__ A, const u16* __restrict__ BT,
                                                  const float* __restrict__ bias, int M, int N, int K,
                                                  float* __restrict__ outF) {
  __shared__ __align__(16) u16 As[3][128 * 32];
  __shared__ __align__(16) u16 Bs[3][128 * 32];
  const int tid = threadIdx.x;
  const int wave = tid >> 6, lane = tid & 63, qd = lane >> 4, ln = lane & 15;
  const int wr = (wave >> 1) * 64, wc = (wave & 1) * 64;
  const int m0 = blockIdx.y * 128, n0 = blockIdx.x * 128;
  f32x4 acc[4][4];
#pragma unroll
  for (int i = 0; i < 4; i++)
#pragma unroll
    for (int j = 0; j < 4; j++) acc[i][j] = (f32x4){0.f, 0.f, 0.f, 0.f};
  const int sr = tid >> 2;
  const int scs = (((tid & 3) ^ ((sr >> 1) & 3))) * 8;
  const u16* gA0 = A + (size_t)(m0 + sr) * K + scs;
  const u16* gA1 = gA0 + (size_t)64 * K;
  const u16* gB0 = BT + (size_t)(n0 + sr) * K + scs;
  const u16* gB1 = gB0 + (size_t)64 * K;
  auto stage = [&](int buf, int kk) {
    gl_lds16(gA0 + kk, &As[buf][wave * 512]);
    gl_lds16(gA1 + kk, &As[buf][2048 + wave * 512]);
    gl_lds16(gB0 + kk, &Bs[buf][wave * 512]);
    gl_lds16(gB1 + kk, &Bs[buf][2048 + wave * 512]);
  };
  const int swz = ((ln >> 1) & 3) << 3;
  auto compute = [&](int buf) {
    bf16x8 af[4], bf[4];
#pragma unroll
    for (int t = 0; t < 4; t++)
      af[t] = *(const bf16x8*)&As[buf][(wr + t * 16 + ln) * 32 + ((qd * 8) ^ swz)];
#pragma unroll
    for (int u = 0; u < 4; u++)
      bf[u] = *(const bf16x8*)&Bs[buf][(wc + u * 16 + ln) * 32 + ((qd * 8) ^ swz)];
#pragma unroll
    for (int mt = 0; mt < 4; mt++)
#pragma unroll
      for (int nt = 0; nt < 4; nt++)
        acc[mt][nt] = __builtin_amdgcn_mfma_f32_16x16x32_bf16(af[mt], bf[nt], acc[mt][nt], 0, 0, 0);
  };
  stage(0, 0);
  stage(1, 32);
  int bufc = 0;
  for (int kk = 64; kk < K; kk += 32) {
    stage((bufc + 2) % 3, kk);
    asm volatile("s_waitcnt vmcnt(8)" ::: "memory");
    __builtin_amdgcn_s_barrier();
    asm volatile("" ::: "memory");
    compute(bufc);
    asm volatile("" ::: "memory");
    __builtin_amdgcn_s_barrier();
    bufc = (bufc + 1) % 3;
  }
  asm volatile("s_waitcnt vmcnt(4)" ::: "memory");
  __builtin_amdgcn_s_barrier();
  asm volatile("" ::: "memory");
  compute(bufc);
  asm volatile("s_waitcnt vmcnt(0)" ::: "memory");
  __builtin_amdgcn_s_barrier();
  asm volatile("" ::: "memory");
  compute((bufc + 1) % 3);
#pragma unroll
  for (int nt = 0; nt < 4; nt++) {
    int col = n0 + wc + nt * 16 + ln;
    float bv = bias[col];
#pragma unroll
    for (int mt = 0; mt < 4; mt++)
#pragma unroll
      for (int r = 0; r < 4; r++) {
        int row = m0 + wr + mt * 16 + qd * 4 + r;
        outF[(size_t)row * N + col] = acc[mt][nt][r] + bv;
      }
  }
}

// Register-q featurize of a 32-el chunk (e = 32*KT + 16*p .. +15) into dst (contiguous 16 u16).
template<int KT>
__device__ __forceinline__ void feat_row(const float* q16, int p, u16* dst) {
  float v[16];
  if (KT == 0 && p == 0) {
    v[0] = 1.0f;
#pragma unroll
    for (int j = 1; j < 16; j++) v[j] = 0.5f * q16[j - 1];
  } else if (KT == 0) {  // p==1: e=16..31
    v[0] = 0.5f * q16[15];
    float wm = C2 * q16[0];
#pragma unroll
    for (int j = 1; j < 16; j++) v[j] = wm * q16[j - 1];
  } else {
    constexpr int c = 2 * KT;
    float wm = C2 * (p ? q16[c]     : q16[c - 1]);
    float w0 = C2 * (p ? q16[c - 1] : q16[c - 2]);
    v[0] = w0 * q16[15];
#pragma unroll
    for (int j = 1; j < 16; j++) v[j] = wm * q16[j - 1];
    if (KT == 8 && p) {  // e >= 273 -> 0
#pragma unroll
      for (int j = 1; j < 16; j++) v[j] = 0.f;
    }
  }
  unsigned w[8];
#pragma unroll
  for (int j = 0; j < 8; j++) w[j] = pk2b(v[2 * j], v[2 * j + 1]);
  *(uint4*)dst = *(uint4*)w;
  *(uint4*)(dst + 8) = *(uint4*)(w + 4);
}

// Register-k featurize for chunk_sums: mt = MTB + 2p -> buffer (mt & 3), [el][t] layout
template<int MTB>
__device__ __forceinline__ void kfeat(const float* k16, int p, int t2, u16 (*kfT)[16][136]) {
  float v[16];
  if (MTB == 0) {
    if (p == 0) {
      v[0] = 1.0f;
#pragma unroll
      for (int j = 1; j < 16; j++) v[j] = 0.5f * k16[j - 1];
    } else {
      float w0 = C2 * k16[0], wm = C2 * k16[1];
      v[0] = w0 * k16[15];
#pragma unroll
      for (int j = 1; j < 16; j++) v[j] = wm * k16[j - 1];
    }
  } else if (MTB == 1) {
    if (p == 0) {
      v[0] = 0.5f * k16[15];
      float wm = C2 * k16[0];
#pragma unroll
      for (int j = 1; j < 16; j++) v[j] = wm * k16[j - 1];
    } else {
      float w0 = C2 * k16[1], wm = C2 * k16[2];
      v[0] = w0 * k16[15];
#pragma unroll
      for (int j = 1; j < 16; j++) v[j] = wm * k16[j - 1];
    }
  } else {
    float wm = C2 * (p ? k16[MTB + 1] : k16[MTB - 1]);
    float w0 = C2 * (p ? k16[MTB]     : k16[MTB - 2]);
    v[0] = w0 * k16[15];
#pragma unroll
    for (int j = 1; j < 16; j++) v[j] = wm * k16[j - 1];
  }
  union { unsigned w[8]; u16 s[16]; } u;
#pragma unroll
  for (int j = 0; j < 8; j++) u.w[j] = pk2b(v[2 * j], v[2 * j + 1]);
  int b = 2 * p + (MTB & 1);
#pragma unroll
  for (int el = 0; el < 16; el++) kfT[b][el][t2] = u.s[el];
}

// Per (b,h,chunk of 128): ckvT[hd][e] = sum_t Kf[t][e]*V[t][hd] (bf16), ck[e] = colsum Kf (fp32)
__global__ __launch_bounds__(256) void chunk_sums(const float* __restrict__ qkw, const u16* __restrict__ vbT,
                                                  u16* __restrict__ ckvT, float* __restrict__ ck) {
  __shared__ float kl[CHK][20];
  __shared__ __align__(16) u16 kfT[4][16][136];
  const int tid = threadIdx.x;
  const int bh = blockIdx.x / NC, c = blockIdx.x % NC;
  const int b = bh >> 4, h = bh & 15;
  const int wave = tid >> 6, lane = tid & 63, qd = lane >> 4, ln = lane & 15;
  const int t2 = tid >> 1, p = tid & 1;
  const size_t rowbase = (size_t)(b * SEQ + c * CHK);
  float k16[16];
  {
    const float* kp = &qkw[(rowbase + t2) * QKS + 256 + h * FEAT];
    float4 v0 = *(const float4*)kp, v1 = *(const float4*)(kp + 4);
    float4 v2 = *(const float4*)(kp + 8), v3 = *(const float4*)(kp + 12);
    k16[0] = v0.x; k16[1] = v0.y; k16[2] = v0.z; k16[3] = v0.w;
    k16[4] = v1.x; k16[5] = v1.y; k16[6] = v1.z; k16[7] = v1.w;
    k16[8] = v2.x; k16[9] = v2.y; k16[10] = v2.z; k16[11] = v2.w;
    k16[12] = v3.x; k16[13] = v3.y; k16[14] = v3.z; k16[15] = v3.w;
    float4 h0, h1;
    if (p == 0) { h0 = v0; h1 = v1; } else { h0 = v2; h1 = v3; }
    *(float4*)&kl[t2][p * 8] = h0;
    *(float4*)&kl[t2][p * 8 + 4] = h1;
  }
  uint4 bVv[4][4];
#pragma unroll
  for (int kk2 = 0; kk2 < 4; kk2++)
#pragma unroll
    for (int nt = 0; nt < 4; nt++)
      bVv[kk2][nt] = *(const uint4*)&vbT[(size_t)(h * HD + nt * 16 + ln) * MROWS +
                                         rowbase + kk2 * 32 + qd * 8];
  const size_t obase = (size_t)(bh * NC + c) * HD;
  auto mstore = [&](int mt, int bufw) {
    f32x4 acc[4];
#pragma unroll
    for (int nt = 0; nt < 4; nt++) acc[nt] = (f32x4){0.f, 0.f, 0.f, 0.f};
#pragma unroll
    for (int kk2 = 0; kk2 < 4; kk2++) {
      bf16x8 a = *(const bf16x8*)&kfT[bufw][ln][kk2 * 32 + qd * 8];
#pragma unroll
      for (int nt = 0; nt < 4; nt++) {
        bf16x8 bb = *(const bf16x8*)&bVv[kk2][nt];
        acc[nt] = __builtin_amdgcn_mfma_f32_16x16x32_bf16(a, bb, acc[nt], 0, 0, 0);
      }
    }
#pragma unroll
    for (int nt = 0; nt < 4; nt++) {
      uint2 pp;
      pp.x = pk2b(acc[nt][0], acc[nt][1]);
      pp.y = pk2b(acc[nt][2], acc[nt][3]);
      *(uint2*)&ckvT[(obase + nt * 16 + ln) * EXPP + mt * 16 + qd * 4] = pp;
    }
  };
  __syncthreads();
  kfeat<0>(k16, p, t2, kfT); kfeat<1>(k16, p, t2, kfT);
  __syncthreads();
  mstore(wave, wave);
  __syncthreads();
  kfeat<4>(k16, p, t2, kfT); kfeat<5>(k16, p, t2, kfT);
  __syncthreads();
  mstore(4 + wave, wave);
  __syncthreads();
  kfeat<8>(k16, p, t2, kfT); kfeat<9>(k16, p, t2, kfT);
  __syncthreads();
  mstore(8 + wave, wave);
  __syncthreads();
  kfeat<12>(k16, p, t2, kfT); kfeat<13>(k16, p, t2, kfT);
  __syncthreads();
  mstore(12 + wave, wave);
  __syncthreads();
  {  // mts 16,17 -> buffers 0,1
    float v[16];
    if (p == 0) {
      float w0 = C2 * k16[14], wm = C2 * k16[15];
      v[0] = w0 * k16[15];
#pragma unroll
      for (int j = 1; j < 16; j++) v[j] = wm * k16[j - 1];
    } else {
      v[0] = C2 * k16[15] * k16[15];
#pragma unroll
      for (int j = 1; j < 16; j++) v[j] = 0.f;
    }
    union { unsigned w[8]; u16 s[16]; } u;
#pragma unroll
    for (int j = 0; j < 8; j++) u.w[j] = pk2b(v[2 * j], v[2 * j + 1]);
#pragma unroll
    for (int el = 0; el < 16; el++) kfT[p][el][t2] = u.s[el];
  }
  __syncthreads();
  if (wave < 2) mstore(16 + wave, wave);
  for (int e = tid; e < EXPP; e += 256) {
    float s = 0.f;
    if (e == 0) s = (float)CHK;
    else if (e < 17) { float t = 0.f; for (int tt = 0; tt < CHK; tt++) t += kl[tt][e - 1]; s = 0.5f * t; }
    else if (e < EXPD) {
      int u = e - 17, i0 = u >> 4, j0 = u & 15; float t = 0.f;
      for (int tt = 0; tt < CHK; tt++) t += kl[tt][i0] * kl[tt][j0];
      s = C2 * t;
    }
    ck[(size_t)(bh * NC + c) * EXPP + e] = s;
  }
}

// Exclusive prefix over chunks (in place, bf16) on ckvT; inclusive final -> out_kv.
__global__ __launch_bounds__(256) void kv_prefix(u16* __restrict__ ckvT, const float* __restrict__ kv0,
                                                 float* __restrict__ out_kv,
                                                 float* __restrict__ ck, const float* __restrict__ k0,
                                                 float* __restrict__ out_k) {
  const int tid = threadIdx.x;
  const int bh = blockIdx.x / 10, eg = blockIdx.x % 10;
  if (eg == 9) {
    for (int e = tid; e < EXPP; e += 256) {
      float S = (e < EXPD) ? k0[(size_t)bh * EXPD + e] : 0.f;
      for (int c = 0; c < NC; c++) {
        size_t idx = ((size_t)bh * NC + c) * EXPP + e;
        float v = ck[idx];
        ck[idx] = S;
        S += v;
      }
      if (e < EXPD) out_k[(size_t)bh * EXPD + e] = S;
    }
    return;
  }
  const int hd = tid >> 2;
  const int e0 = eg * 32 + (tid & 3) * 8;
  float S[8];
#pragma unroll
  for (int j = 0; j < 8; j++) {
    int e = e0 + j;
    S[j] = (e < EXPD) ? kv0[((size_t)bh * EXPD + e) * HD + hd] : 0.f;
  }
  u16* base = ckvT + ((size_t)bh * NC * HD + hd) * EXPP + e0;
  const size_t cstride = (size_t)HD * EXPP;
  uint4 v0 = *(const uint4*)base;
  uint4 v1 = *(const uint4*)(base + cstride);
  for (int c = 0; c < NC; c++) {
    uint4 vn = v1;
    if (c + 2 < NC) vn = *(const uint4*)(base + (size_t)(c + 2) * cstride);
    union { uint4 q; unsigned w[4]; } pk;
#pragma unroll
    for (int j = 0; j < 4; j++) pk.w[j] = pk2b(S[2 * j], S[2 * j + 1]);
    *(uint4*)(base + (size_t)c * cstride) = pk.q;
    union { uint4 q; u16 s[8]; } vv; vv.q = v0;
#pragma unroll
    for (int j = 0; j < 8; j++) S[j] += b2f(vv.s[j]);
    v0 = v1; v1 = vn;
  }
#pragma unroll
  for (int j = 0; j < 8; j++) {
    int e = e0 + j;
    if (e < EXPD) out_kv[((size_t)bh * EXPD + e) * HD + hd] = S[j];
  }
}

// Per (b,h,chunk of 128): O = (Qf@S + mask_incl(poly(QK^T))@V) / den.
// R10: R8/R9 structure + __launch_bounds__(256, 3). LDS (53,248B) caps this
// kernel at 3 blocks/CU regardless of VGPR, so declare exactly that occupancy:
// VGPR budget 512/3 ~ 170 >= ~150 true need -> no spill. (R9's un-bounded
// compile chose 68 VGPR + scratch spills: WRITE +5MB, FETCH +6MB, dur 42->56.)
__global__ __launch_bounds__(256, 3) void out_chunk(const float* __restrict__ qkw, const u16* __restrict__ vbT,
                                                    const u16* __restrict__ ckvT, const float* __restrict__ ck,
                                                    u16* __restrict__ ob) {
  __shared__ __align__(16) u16 pool[25600];   // 51,200 B
  __shared__ float kstl[EXPP];
  __shared__ float denl[CHK];
  u16 (*qlb)[16] = (u16(*)[16])pool;                  // 128x16 (no zero half)
  u16 (*klb)[16] = (u16(*)[16])(pool + 2048);         // 128x16 (no zero half)
  u16* zslab     = pool + 4096;                       // 8 u16 shared zeros (16B)
  u16 (*qf0)[40] = (u16(*)[40])(pool + 4104);         // Qf quad buffers
  u16 (*qf1)[40] = (u16(*)[40])(pool + 9224);
  u16 (*qf2)[40] = (u16(*)[40])(pool + 14344);
  u16 (*qf3)[40] = (u16(*)[40])(pool + 19464);        // ends 24,584
  u16 (*alB)[72] = (u16(*)[72])pool;                  // scores s=64..127 (overlays qlb/klb/zslab/qf0-head)
  u16 (*alA)[72] = (u16(*)[72])(pool + 9216);         // scores s=0..63   (overlays qf1/qf2-head)
  const int tid = threadIdx.x;
  const int bh = blockIdx.x / NC, c = blockIdx.x % NC;
  const int b = bh >> 4, h = bh & 15;
  const int wave = tid >> 6, lane = tid & 63, qd = lane >> 4, ln = lane & 15;
  const int t2 = tid >> 1, p = tid & 1;
  const size_t rowbase = (size_t)(b * SEQ + c * CHK);
  float q16[16];
  {
    const float* qp = &qkw[(rowbase + t2) * QKS + h * FEAT];
    float4 v0 = *(const float4*)qp, v1 = *(const float4*)(qp + 4);
    float4 v2 = *(const float4*)(qp + 8), v3 = *(const float4*)(qp + 12);
    q16[0] = v0.x; q16[1] = v0.y; q16[2] = v0.z; q16[3] = v0.w;
    q16[4] = v1.x; q16[5] = v1.y; q16[6] = v1.z; q16[7] = v1.w;
    q16[8] = v2.x; q16[9] = v2.y; q16[10] = v2.z; q16[11] = v2.w;
    q16[12] = v3.x; q16[13] = v3.y; q16[14] = v3.z; q16[15] = v3.w;
    unsigned qw[4];
#pragma unroll
    for (int j = 0; j < 4; j++) qw[j] = pk2b(q16[p * 8 + 2 * j], q16[p * 8 + 2 * j + 1]);
    *(uint4*)&qlb[t2][p * 8] = *(uint4*)qw;
    const float* kp = &qkw[(rowbase + t2) * QKS + 256 + h * FEAT + p * 8];
    float4 k0v = *(const float4*)kp, k1v = *(const float4*)(kp + 4);
    unsigned kw[4] = {pk2b(k0v.x, k0v.y), pk2b(k0v.z, k0v.w),
                      pk2b(k1v.x, k1v.y), pk2b(k1v.z, k1v.w)};
    *(uint4*)&klb[t2][p * 8] = *(uint4*)kw;
    if (tid == 0) *(uint4*)zslab = (uint4){0u, 0u, 0u, 0u};
  }
  const size_t cbase = (size_t)(bh * NC + c);
  for (int e = tid; e < EXPP; e += 256) kstl[e] = ck[cbase * EXPP + e];
  const u16* sptr = ckvT + (cbase * HD + wave * 16 + ln) * EXPP + qd * 8;
  // 4-slot rolling S-fragment buffer: slot = kt & 3; pairs prefetched 1 phase ahead
  uint4 bSv[4];
  bSv[0] = *(const uint4*)(sptr + 0 * 32);
  bSv[1] = *(const uint4*)(sptr + 1 * 32);
  feat_row<0>(q16, p, &qf0[t2][p * 16]);
  feat_row<1>(q16, p, &qf1[t2][p * 16]);
  f32x4 accO[8];
#pragma unroll
  for (int nt = 0; nt < 8; nt++) accO[nt] = (f32x4){0.f, 0.f, 0.f, 0.f};
  // per chunk: 4+4 bQ sub-batched MFMA (R7 style), setprio around MFMA
#define CHUNK(KT, QF)                                                                      \
  {                                                                                        \
    bf16x8 aS = *(const bf16x8*)&bSv[(KT) & 3];                                            \
    bf16x8 bq0[4];                                                                         \
    _Pragma("unroll")                                                                      \
    for (int nt = 0; nt < 4; nt++) bq0[nt] = *(const bf16x8*)&QF[nt * 16 + ln][qd * 8];    \
    __builtin_amdgcn_s_setprio(1);                                                         \
    _Pragma("unroll")                                                                      \
    for (int nt = 0; nt < 4; nt++)                                                         \
      accO[nt] = __builtin_amdgcn_mfma_f32_16x16x32_bf16(aS, bq0[nt], accO[nt], 0, 0, 0);  \
    _Pragma("unroll")                                                                      \
    for (int nt = 4; nt < 8; nt++) {                                                       \
      bf16x8 bq1 = *(const bf16x8*)&QF[nt * 16 + ln][qd * 8];                              \
      accO[nt] = __builtin_amdgcn_mfma_f32_16x16x32_bf16(aS, bq1, accO[nt], 0, 0, 0);      \
    }                                                                                      \
    __builtin_amdgcn_s_setprio(0);                                                         \
  }
  // PH0: chunks 0,1 (qf0,qf1); prefetch S2,S3; feat 2,3 -> qf2,qf3
  __syncthreads();
  bSv[2] = *(const uint4*)(sptr + 2 * 32);
  bSv[3] = *(const uint4*)(sptr + 3 * 32);
  CHUNK(0, qf0)
  feat_row<2>(q16, p, &qf2[t2][p * 16]);
  CHUNK(1, qf1)
  feat_row<3>(q16, p, &qf3[t2][p * 16]);
  // PH1: chunks 2,3 (qf2,qf3); prefetch S4,S5; feat 4,5 -> qf0,qf1
  __syncthreads();
  bSv[0] = *(const uint4*)(sptr + 4 * 32);
  bSv[1] = *(const uint4*)(sptr + 5 * 32);
  CHUNK(2, qf2)
  feat_row<4>(q16, p, &qf0[t2][p * 16]);
  CHUNK(3, qf3)
  feat_row<5>(q16, p, &qf1[t2][p * 16]);
  // PH2: chunks 4,5 (qf0,qf1); prefetch S6,S7; feat 6,7 -> qf2,qf3
  __syncthreads();
  bSv[2] = *(const uint4*)(sptr + 6 * 32);
  bSv[3] = *(const uint4*)(sptr + 7 * 32);
  CHUNK(4, qf0)
  feat_row<6>(q16, p, &qf2[t2][p * 16]);
  CHUNK(5, qf1)
  feat_row<7>(q16, p, &qf3[t2][p * 16]);
  // PH3: chunks 6,7 (qf2,qf3); prefetch S8 -> slot 0; feat 8 -> qf0
  __syncthreads();
  bSv[0] = *(const uint4*)(sptr + 8 * 32);
  CHUNK(6, qf2)
  feat_row<8>(q16, p, &qf0[t2][p * 16]);
  CHUNK(7, qf3)
  // FIN: chunk 8 (qf0), aS = bSv[8&3=0]
  __syncthreads();
  CHUNK(8, qf0)
#undef CHUNK
  __syncthreads();   // all waves done reading qf buffers -> alA region free
  // hoisted denominator polynomial (q16 dies here; before scores)
  float s_poly;
  {
    float s = 0.f;
#pragma unroll
    for (int i2 = 0; i2 < 8; i2++) {
      int i = p * 8 + i2;
      float inner = 0.f;
#pragma unroll
      for (int j = 0; j < 16; j++) inner += q16[j] * kstl[17 + i * 16 + j];
      s += q16[i] * inner;
    }
    s *= C2;
    float s1 = 0.f;
#pragma unroll
    for (int j2 = 0; j2 < 8; j2++) s1 += q16[p * 8 + j2] * kstl[1 + p * 8 + j2];
    s += 0.5f * s1;
    if (p == 0) s += kstl[0] + 1e-6f;
    s_poly = s;
  }
  // scores st2=0: s-tile = wave (s 0..63) -> alA. K=32 MFMA with zero-slab for
  // the k>=16 half: lanes qd>=2 read the shared 16B zero row (broadcast, free).
  {
    const u16* kap = (qd < 2) ? &klb[wave * 16 + ln][qd * 8] : zslab;
    bf16x8 aK = *(const bf16x8*)kap;
#pragma unroll
    for (int nn = 0; nn < 2; nn++) {
      f32x4 accU[4];
      __builtin_amdgcn_s_setprio(1);
#pragma unroll
      for (int j = 0; j < 4; j++) {
        const u16* qap = (qd < 2) ? &qlb[(nn * 4 + j) * 16 + ln][qd * 8] : zslab;
        bf16x8 bQ = *(const bf16x8*)qap;
        accU[j] = __builtin_amdgcn_mfma_f32_16x16x32_bf16(aK, bQ, (f32x4){0.f, 0.f, 0.f, 0.f}, 0, 0, 0);
      }
      __builtin_amdgcn_s_setprio(0);
#pragma unroll
      for (int j = 0; j < 4; j++) {
        int t = (nn * 4 + j) * 16 + ln, sb = wave * 16 + qd * 4;
        float scm[4];
#pragma unroll
        for (int r = 0; r < 4; r++) {
          float u = accU[j][r];
          float sc = 1.f + 0.25f * u + 0.03125f * u * u;
          scm[r] = (sb + r <= t) ? sc : 0.f;
        }
        uint2 pp; pp.x = pk2b(scm[0], scm[1]); pp.y = pk2b(scm[2], scm[3]);
        *(uint2*)&alA[t][sb] = pp;
      }
    }
  }
  // scores st2=1: s-tile = wave+4 (s 64..127) -> alB (overlays qlb/klb; must
  // finish ALL reads before any write -> accU[8] held across the barrier).
  {
    f32x4 accU[8];
    const u16* kap = (qd < 2) ? &klb[(wave + 4) * 16 + ln][qd * 8] : zslab;
    bf16x8 aK = *(const bf16x8*)kap;
    __builtin_amdgcn_s_setprio(1);
#pragma unroll
    for (int nt = 0; nt < 8; nt++) {
      const u16* qap = (qd < 2) ? &qlb[nt * 16 + ln][qd * 8] : zslab;
      bf16x8 bQ = *(const bf16x8*)qap;
      accU[nt] = __builtin_amdgcn_mfma_f32_16x16x32_bf16(aK, bQ, (f32x4){0.f, 0.f, 0.f, 0.f}, 0, 0, 0);
    }
    __builtin_amdgcn_s_setprio(0);
    // V fragments issued here: latency hides under alB pack/write + barrier
    uint4 bVv[4];
#pragma unroll
    for (int kk2 = 0; kk2 < 4; kk2++)
      bVv[kk2] = *(const uint4*)&vbT[(size_t)(h * HD + wave * 16 + ln) * MROWS +
                                     rowbase + kk2 * 32 + qd * 8];
    __syncthreads();   // all qlb/klb/zslab reads complete before alB overwrite
#pragma unroll
    for (int nt = 0; nt < 8; nt++) {
      int t = nt * 16 + ln, sbl = wave * 16 + qd * 4;
      float scm[4];
#pragma unroll
      for (int r = 0; r < 4; r++) {
        float u = accU[nt][r];
        float sc = 1.f + 0.25f * u + 0.03125f * u * u;
        scm[r] = (64 + sbl + r <= t) ? sc : 0.f;
      }
      uint2 pp; pp.x = pk2b(scm[0], scm[1]); pp.y = pk2b(scm[2], scm[3]);
      *(uint2*)&alB[t][sbl] = pp;
    }
    __syncthreads();
    // A@V: A = V frags (registers), B = al rows
    __builtin_amdgcn_s_setprio(1);
#pragma unroll
    for (int kk2 = 0; kk2 < 4; kk2++) {
      bf16x8 aV = *(const bf16x8*)&bVv[kk2];
#pragma unroll
      for (int nt = 0; nt < 8; nt++) {
        bf16x8 bA = (kk2 < 2) ? *(const bf16x8*)&alA[nt * 16 + ln][kk2 * 32 + qd * 8]
                              : *(const bf16x8*)&alB[nt * 16 + ln][(kk2 - 2) * 32 + qd * 8];
        accO[nt] = __builtin_amdgcn_mfma_f32_16x16x32_bf16(aV, bA, accO[nt], 0, 0, 0);
      }
    }
    __builtin_amdgcn_s_setprio(0);
  }
  // denominator: row-sum of al + hoisted polynomial
  {
    const u16* arow = p ? &alB[t2][0] : &alA[t2][0];
    float da = 0.f;
#pragma unroll
    for (int sb = 0; sb < 8; sb++) {
      union { uint4 q; u16 hh[8]; } uu;
      uu.q = *(const uint4*)(arow + sb * 8);
#pragma unroll
      for (int j = 0; j < 8; j++) da += b2f(uu.hh[j]);
    }
    float s = s_poly + da;
    s += __shfl_xor(s, 1);
    if (p == 0) denl[t2] = s;
  }
  __syncthreads();
  // output: lane holds hd = wave*16+qd*4+r, t = nt*16+ln -> packed uint2 along hd
#pragma unroll
  for (int nt = 0; nt < 8; nt++) {
    int t = nt * 16 + ln;
    float rd = 1.0f / denl[t];
    uint2 pp;
    pp.x = pk2b(accO[nt][0] * rd, accO[nt][1] * rd);
    pp.y = pk2b(accO[nt][2] * rd, accO[nt][3] * rd);
    *(uint2*)&ob[(rowbase + t) * DM + h * HD + wave * 16 + qd * 4] = pp;
  }
}

extern "C" void kernel_launch(void* const* d_in, const int* in_sizes, int n_in,
                              void* d_out, int out_size, void* d_ws, size_t ws_size,
                              hipStream_t stream) {
  (void)in_sizes; (void)n_in; (void)out_size;
  const float* x   = (const float*)d_in[0];
  const float* kv0 = (const float*)d_in[1];
  const float* k0  = (const float*)d_in[2];
  const float* bq  = (const float*)d_in[4];
  const float* bk  = (const float*)d_in[6];
  const float* bv  = (const float*)d_in[8];
  const float* bo  = (const float*)d_in[10];
  float* out = (float*)d_out;
  char* ws = (char*)d_ws;
  size_t off = 0;
  auto take = [&](size_t bytes) { char* p = ws + off; off += (bytes + 255) & ~(size_t)255; return p; };
  u16*   xb     = (u16*)  take((size_t)BATCH * SEQ * DM * 2);
  u16*   wqkvT  = (u16*)  take((size_t)1536 * DM * 2);
  u16*   woT    = (u16*)  take((size_t)DM * DM * 2);
  float* bias_a = (float*)take((size_t)1536 * 4);
  float* qkw    = (float*)take((size_t)BATCH * SEQ * QKS * 4);
  u16*   vbT    = (u16*)  take((size_t)BATCH * SEQ * DM * 2);
  u16*   ckvT   = (u16*)  take((size_t)BH * NC * EXPP * HD * 2);
  float* ck     = (float*)take((size_t)BH * NC * EXPP * 4);
  u16*   ob     = (u16*)  take((size_t)BATCH * SEQ * DM * 2);
  if (off > ws_size) return;

  float* out_kv = out + (size_t)BATCH * SEQ * DM;
  float* out_k  = out_kv + (size_t)BH * EXPD * HD;

  prep<<<8192 + 2560 + 6, 256, 0, stream>>>(x, xb,
      (const float*)d_in[3], (const float*)d_in[5], (const float*)d_in[7], (const float*)d_in[9],
      wqkvT, woT, bq, bk, bv, bias_a);

  gemmQKV<<<dim3(8, 64), 256, 0, stream>>>(xb, wqkvT, bias_a, qkw, vbT);

  chunk_sums<<<BH * NC, 256, 0, stream>>>(qkw, vbT, ckvT, ck);
  kv_prefix<<<BH * 10, 256, 0, stream>>>(ckvT, kv0, out_kv, ck, k0, out_k);
  out_chunk<<<BH * NC, 256, 0, stream>>>(qkw, vbT, ckvT, ck, ob);

  gemm128<<<dim3(8, 64), 256, 0, stream>>>(ob, woT, bo, MROWS, DM, DM, out);
}